// Round 7
// baseline (662.703 us; speedup 1.0000x reference)
//
#include <hip/hip_runtime.h>
#include <cstdio>

#define B_ 32
#define S_ 512
#define D_ 1024
#define H_ 512
#define K_ 16
#define L_ 16
#define NT_ 16
#define NSEQ 512      // B*K
#define XROWS 8192    // NSEQ*L
#define G4H 2048      // 4*H
#define OUTC 2080
#define MROWS 528     // NSEQ + NT

typedef unsigned short u16;
typedef __bf16 bf16x8 __attribute__((ext_vector_type(8)));
typedef float f32x4 __attribute__((ext_vector_type(4)));

__device__ inline u16 f2b(float f) {
  union { float f; unsigned u; } x; x.f = f;
  unsigned r = x.u + 0x7FFFu + ((x.u >> 16) & 1u);
  return (u16)(r >> 16);
}
__device__ inline float b2f(u16 h) {
  union { unsigned u; float f; } c; c.u = ((unsigned)h) << 16;
  return c.f;
}
__device__ inline float sigf(float x) { return 1.0f / (1.0f + expf(-x)); }
__device__ inline float wredsum(float v) {
#pragma unroll
  for (int off = 32; off > 0; off >>= 1) v += __shfl_xor(v, off);
  return v;
}
// async global->LDS, 16B/lane; dest = wave-uniform base + lane*16 (linear)
__device__ inline void gl16(const u16* g, u16* l) {
  __builtin_amdgcn_global_load_lds(
      (const __attribute__((address_space(1))) unsigned int*)g,
      (__attribute__((address_space(3))) unsigned int*)l, 16, 0, 0);
}

// ---- LDS swizzle (rule #21: linear gl16 dest + inverse-permuted global src +
// same-permuted read). rows paired into 128B superrows of 8 16B chunks;
// slot = chunkidx ^ (superrow&7).
__device__ inline int swzidx(int R, int c) {
  return (R >> 1) * 64 + (((((R & 1) << 2) | c) ^ ((R >> 1) & 7)) << 3);
}
__device__ inline void stage_map(int wave, int lane, int j, int& lrow, int& cu) {
  int sr = j * 32 + wave * 8 + (lane >> 3);
  int ci = (lane & 7) ^ (sr & 7);
  lrow = sr * 2 + (ci >> 2);
  cu = (ci & 3) * 8;
}

// ---------------- split f32 -> hi+lo bf16 ----------------
__global__ __launch_bounds__(256) void split_kernel(const float* __restrict__ in,
                                                    u16* __restrict__ hi,
                                                    u16* __restrict__ lo, int n) {
  int i = blockIdx.x * 256 + threadIdx.x;
  if (i >= n) return;
  float x = in[i];
  u16 h = f2b(x);
  hi[i] = h;
  lo[i] = f2b(x - b2f(h));
}

// 4 MLP weights in one launch: blockIdx.y selects
__global__ __launch_bounds__(256) void split4_kernel(
    const float* __restrict__ s0, const float* __restrict__ s1,
    const float* __restrict__ s2, const float* __restrict__ s3,
    u16* __restrict__ h0, u16* __restrict__ l0,
    u16* __restrict__ h1, u16* __restrict__ l1,
    u16* __restrict__ h2, u16* __restrict__ l2,
    u16* __restrict__ h3, u16* __restrict__ l3) {
  const float* src = blockIdx.y == 0 ? s0 : blockIdx.y == 1 ? s1 : blockIdx.y == 2 ? s2 : s3;
  u16* hi = blockIdx.y == 0 ? h0 : blockIdx.y == 1 ? h1 : blockIdx.y == 2 ? h2 : h3;
  u16* lo = blockIdx.y == 0 ? l0 : blockIdx.y == 1 ? l1 : blockIdx.y == 2 ? l2 : l3;
  int i = blockIdx.x * 256 + threadIdx.x;
  float x = src[i];
  u16 h = f2b(x);
  hi[i] = h;
  lo[i] = f2b(x - b2f(h));
}

__global__ __launch_bounds__(256) void hsplit_kernel(const float* __restrict__ in,
                                                     u16* __restrict__ hi,
                                                     u16* __restrict__ lo) {
  size_t i = ((size_t)blockIdx.x * 256 + threadIdx.x) * 4;
  float4 v = *reinterpret_cast<const float4*>(in + i);
  float a[4] = {v.x, v.y, v.z, v.w};
#pragma unroll
  for (int j = 0; j < 4; ++j) {
    u16 h = f2b(a[j]);
    hi[i + j] = h;
    lo[i + j] = f2b(a[j] - b2f(h));
  }
}

__global__ __launch_bounds__(256) void icast_kernel(const float* __restrict__ W,
                                                    u16* __restrict__ out, int Kd) {
  int rp = blockIdx.x;
  int j = rp >> 2, g = rp & 3;
  const float* src = W + ((size_t)(g * H_ + j)) * Kd;
  u16* dst = out + (size_t)rp * Kd;
  for (int k = threadIdx.x; k < Kd; k += 256) dst[k] = f2b(src[k]);
}

__global__ __launch_bounds__(256) void bsum_kernel(const float* __restrict__ bih,
                                                   const float* __restrict__ bhh,
                                                   float* __restrict__ bsum) {
  int rp = blockIdx.x * 256 + threadIdx.x;
  if (rp >= G4H) return;
  int j = rp >> 2, g = rp & 3;
  bsum[rp] = bih[g * H_ + j] + bhh[g * H_ + j];
}

// ---- big input GEMM, gather fused, swizzled LDS, 3-buf counted-vmcnt pipeline
// M-index row' = t*NSEQ + seq  (t-major G2 with CONTIGUOUS row-major store).
// source A row for row' is hidden[b(seq)][span_idx[seq*L + t]].
__global__ __launch_bounds__(256) void big_gemm_kernel(
    const u16* __restrict__ Hh, const int* __restrict__ span_idx,
    const u16* __restrict__ Wih2, u16* __restrict__ G2) {
  __shared__ u16 As[3][128 * 32];
  __shared__ u16 Bs[3][128 * 32];
  const int tid = threadIdx.x;
  const int bn = blockIdx.x * 128, bm = blockIdx.y * 128;
  const int wave = tid >> 6, lane = tid & 63;
  const int wm = (wave >> 1) * 64, wn = (wave & 1) * 64;
  const int fr = lane & 15;
  const int cc = lane >> 4;

  const u16* asrc[2];
  const u16* bsrc[2];
  int doff[2];
#pragma unroll
  for (int j = 0; j < 2; ++j) {
    int lrow, cu;
    stage_map(wave, lane, j, lrow, cu);
    int gr = bm + lrow;                     // row' = t*NSEQ + seq
    int t = gr >> 9;
    int seq = gr & 511;
    int b = seq >> 4;
    int sidx = span_idx[seq * L_ + t];
    asrc[j] = Hh + ((size_t)(b * S_ + sidx)) * D_ + cu;
    bsrc[j] = Wih2 + (size_t)(bn + lrow) * D_ + cu;
    doff[j] = (j * 256 + wave * 64) * 8;
  }
  int aoff[4], boff[4];
#pragma unroll
  for (int m = 0; m < 4; ++m) aoff[m] = swzidx(wm + m * 16 + fr, cc);
#pragma unroll
  for (int n = 0; n < 4; ++n) boff[n] = swzidx(wn + n * 16 + fr, cc);

  f32x4 acc[4][4] = {};
  auto STAGE = [&](int buf, int k0) {
    gl16(asrc[0] + k0, &As[buf][doff[0]]);
    gl16(asrc[1] + k0, &As[buf][doff[1]]);
    gl16(bsrc[0] + k0, &Bs[buf][doff[0]]);
    gl16(bsrc[1] + k0, &Bs[buf][doff[1]]);
  };
  const int NK = D_ / 32;                   // 32
  STAGE(0, 0);
  STAGE(1, 32);
  for (int j = 0; j < NK; ++j) {
    if (j + 1 < NK) asm volatile("s_waitcnt vmcnt(4)" ::: "memory");
    else            asm volatile("s_waitcnt vmcnt(0)" ::: "memory");
    __builtin_amdgcn_s_barrier();
    if (j + 2 < NK) STAGE((j + 2) % 3, (j + 2) * 32);
    const int cur = j % 3;
    bf16x8 af[4], bfr[4];
#pragma unroll
    for (int m = 0; m < 4; ++m) af[m] = *reinterpret_cast<const bf16x8*>(&As[cur][aoff[m]]);
#pragma unroll
    for (int n = 0; n < 4; ++n) bfr[n] = *reinterpret_cast<const bf16x8*>(&Bs[cur][boff[n]]);
#pragma unroll
    for (int m = 0; m < 4; ++m)
#pragma unroll
      for (int n = 0; n < 4; ++n)
        acc[m][n] = __builtin_amdgcn_mfma_f32_16x16x32_bf16(af[m], bfr[n], acc[m][n], 0, 0, 0);
  }
  const int ci = lane & 15;
  const int r0 = (lane >> 4) * 4;
#pragma unroll
  for (int m = 0; m < 4; ++m)
#pragma unroll
    for (int n = 0; n < 4; ++n) {
      int col = bn + wn + n * 16 + ci;
#pragma unroll
      for (int r = 0; r < 4; ++r) {
        int row = bm + wm + m * 16 + r0 + r;    // row' (t-major), contiguous store
        G2[(size_t)row * 4096 + col] = f2b(acc[m][n][r]);
      }
    }
}

// ---------------- fused recurrent GEMM + LSTM gate step, 3-buf pipeline ------
__global__ __launch_bounds__(256) void lstm_step_kernel(
    const u16* __restrict__ hbf_in,
    const u16* __restrict__ Whhf, const u16* __restrict__ Whhb,
    const u16* __restrict__ G2,
    const float* __restrict__ bsumf, const float* __restrict__ bsumb,
    const float* __restrict__ mask,
    float* __restrict__ hst, float* __restrict__ cst,
    u16* __restrict__ hbf_out,
    float* __restrict__ sf,
    int t, int first) {
  __shared__ u16 As[3][64 * 32];
  __shared__ u16 Bs[3][64 * 32];
  const int tid = threadIdx.x;
  const int bz = blockIdx.z;
  const int treal = bz ? (L_ - 1 - t) : t;
  const u16* Whh = bz ? Whhb : Whhf;
  const float* bsum = bz ? bsumb : bsumf;
  const size_t sofs = (size_t)bz * NSEQ * H_;
  const int bm = blockIdx.y * 64, bn = blockIdx.x * 64;
  const int wave = tid >> 6, lane = tid & 63;
  const int wm = (wave >> 1) * 32, wn = (wave & 1) * 32;
  f32x4 acc[2][2] = {};
  const int fr = lane & 15;
  const int cc = lane >> 4;

  if (!first) {
    int lrow, cu;
    stage_map(wave, lane, 0, lrow, cu);
    const u16* asrc = hbf_in + sofs + (size_t)(bm + lrow) * H_ + cu;
    const u16* bsrc = Whh + (size_t)(bn + lrow) * H_ + cu;
    const int doff = wave * 64 * 8;
    int aoff[2], boff[2];
#pragma unroll
    for (int m = 0; m < 2; ++m) aoff[m] = swzidx(wm + m * 16 + fr, cc);
#pragma unroll
    for (int n = 0; n < 2; ++n) boff[n] = swzidx(wn + n * 16 + fr, cc);

    auto STAGE = [&](int buf, int k0) {
      gl16(asrc + k0, &As[buf][doff]);
      gl16(bsrc + k0, &Bs[buf][doff]);
    };
    const int NK = H_ / 32;                 // 16
    STAGE(0, 0);
    STAGE(1, 32);
    for (int j = 0; j < NK; ++j) {
      if (j + 1 < NK) asm volatile("s_waitcnt vmcnt(2)" ::: "memory");
      else            asm volatile("s_waitcnt vmcnt(0)" ::: "memory");
      __builtin_amdgcn_s_barrier();
      if (j + 2 < NK) STAGE((j + 2) % 3, (j + 2) * 32);
      const int cur = j % 3;
      bf16x8 af[2], bfr[2];
#pragma unroll
      for (int m = 0; m < 2; ++m) af[m] = *reinterpret_cast<const bf16x8*>(&As[cur][aoff[m]]);
#pragma unroll
      for (int n = 0; n < 2; ++n) bfr[n] = *reinterpret_cast<const bf16x8*>(&Bs[cur][boff[n]]);
#pragma unroll
      for (int m = 0; m < 2; ++m)
#pragma unroll
        for (int n = 0; n < 2; ++n)
          acc[m][n] = __builtin_amdgcn_mfma_f32_16x16x32_bf16(af[m], bfr[n], acc[m][n], 0, 0, 0);
    }
  }

  const int ci = lane & 15;
  const int r0 = (lane >> 4) * 4;
  const int q = lane & 3;
#pragma unroll
  for (int m = 0; m < 2; ++m)
#pragma unroll
    for (int n = 0; n < 2; ++n) {
      int c = bn + wn + n * 16 + ci;
      int rowbase = bm + wm + m * 16 + r0;
      float val[4];
#pragma unroll
      for (int r = 0; r < 4; ++r) {
        int nrow = rowbase + r;
        float g2 = b2f(G2[((size_t)treal * NSEQ + nrow) * 4096 + (size_t)bz * 2048 + c]);
        val[r] = acc[m][n][r] + g2 + bsum[c];
      }
      float x1[4], x2[4], x3[4];
#pragma unroll
      for (int r = 0; r < 4; ++r) {
        x1[r] = __shfl_xor(val[r], 1);
        x2[r] = __shfl_xor(val[r], 2);
        x3[r] = __shfl_xor(x1[r], 2);
      }
      if (q == 0) {
        int j = c >> 2;
#pragma unroll
        for (int r = 0; r < 4; ++r) {
          int nrow = rowbase + r;
          float gi = val[r], gf = x1[r], gg = x2[r], go = x3[r];
          float mv = mask[nrow * L_ + treal];
          size_t sidx = sofs + (size_t)nrow * H_ + j;
          float co = first ? 0.f : cst[sidx];
          float ho = first ? 0.f : hst[sidx];
          float cn = sigf(gf) * co + sigf(gi) * tanhf(gg);
          float hn = sigf(go) * tanhf(cn);
          float hnew = mv * hn + (1.f - mv) * ho;
          float cnew = mv * cn + (1.f - mv) * co;
          hst[sidx] = hnew;
          cst[sidx] = cnew;
          hbf_out[sidx] = f2b(hnew);
          size_t fidx = (size_t)nrow * 1024 + bz * 512 + j;
          float contrib = hnew * mv;
          if (first) sf[fidx] = contrib;
          else sf[fidx] += contrib;
        }
      }
    }
}

// ---------------- slot_feats: out cols [0,1024) + hi/lo split ----------------
__global__ __launch_bounds__(256) void copy_sf_split_kernel(const float* __restrict__ sf,
                                                            float* __restrict__ out,
                                                            u16* __restrict__ sfh,
                                                            u16* __restrict__ sfl) {
  int bk = blockIdx.x;
  for (int d = threadIdx.x; d < 1024; d += 256) {
    size_t i = (size_t)bk * 1024 + d;
    float v = sf[i];
    out[(size_t)bk * OUTC + d] = v;
    u16 h = f2b(v);
    sfh[i] = h;
    sfl[i] = f2b(v - b2f(h));
  }
}

// ---------------- attn = sf . hidden^T (3-term), masked, f32 out, swizzled ----
__global__ __launch_bounds__(256) void attn_mfma_kernel(
    const u16* __restrict__ sfh, const u16* __restrict__ sfl,
    const u16* __restrict__ Hh, const u16* __restrict__ Hl,
    const int* __restrict__ sstart, const int* __restrict__ send,
    const int* __restrict__ len,
    float* __restrict__ attn_f) {
  __shared__ u16 Bh[128 * 32];
  __shared__ u16 Bl[128 * 32];
  const int b = blockIdx.x;
  const int s0 = blockIdx.y * 128;
  const int tid = threadIdx.x;
  const int wave = tid >> 6, lane = tid & 63;
  const int fr = lane & 15;
  const int cc = lane >> 4;
  const int kg = cc * 8;
  f32x4 acc[2] = {};

  const u16* hsrc[2];
  const u16* lsrc[2];
  int doff[2];
#pragma unroll
  for (int j = 0; j < 2; ++j) {
    int lrow, cu;
    stage_map(wave, lane, j, lrow, cu);
    size_t goff = ((size_t)b * S_ + s0 + lrow) * D_ + cu;
    hsrc[j] = Hh + goff;
    lsrc[j] = Hl + goff;
    doff[j] = (j * 256 + wave * 64) * 8;
  }
  int boff[2];
#pragma unroll
  for (int nt = 0; nt < 2; ++nt) boff[nt] = swzidx(wave * 32 + nt * 16 + fr, cc);

  for (int k0 = 0; k0 < D_; k0 += 32) {
    gl16(hsrc[0] + k0, &Bh[doff[0]]);
    gl16(hsrc[1] + k0, &Bh[doff[1]]);
    gl16(lsrc[0] + k0, &Bl[doff[0]]);
    gl16(lsrc[1] + k0, &Bl[doff[1]]);
    __syncthreads();
    size_t aoff = ((size_t)b * 16 + fr) * D_ + k0 + kg;
    bf16x8 ah = *reinterpret_cast<const bf16x8*>(sfh + aoff);
    bf16x8 al = *reinterpret_cast<const bf16x8*>(sfl + aoff);
#pragma unroll
    for (int nt = 0; nt < 2; ++nt) {
      bf16x8 bh = *reinterpret_cast<const bf16x8*>(&Bh[boff[nt]]);
      bf16x8 bl = *reinterpret_cast<const bf16x8*>(&Bl[boff[nt]]);
      acc[nt] = __builtin_amdgcn_mfma_f32_16x16x32_bf16(ah, bh, acc[nt], 0, 0, 0);
      acc[nt] = __builtin_amdgcn_mfma_f32_16x16x32_bf16(ah, bl, acc[nt], 0, 0, 0);
      acc[nt] = __builtin_amdgcn_mfma_f32_16x16x32_bf16(al, bh, acc[nt], 0, 0, 0);
    }
    __syncthreads();
  }
  const int ln = len[b];
#pragma unroll
  for (int nt = 0; nt < 2; ++nt) {
    int s = s0 + wave * 32 + nt * 16 + (lane & 15);
#pragma unroll
    for (int r = 0; r < 4; ++r) {
      int krow = (lane >> 4) * 4 + r;
      int bk = b * 16 + krow;
      int st = sstart[bk], en = send[bk];
      bool cm = (s < st) || ((s > en) && (s < ln));
      attn_f[(size_t)bk * S_ + s] = cm ? acc[nt][r] : 0.f;
    }
  }
}

// ---------------- context (exact f32): out[.,1024+d] = sum_s attn*hidden ----
__global__ __launch_bounds__(256) void ctx_f32_kernel(
    const float* __restrict__ attn_f, const float* __restrict__ hidden,
    float* __restrict__ out) {
  __shared__ float att[16 * 512];   // 32 KB
  const int b = blockIdx.x;
  const int d0 = blockIdx.y * 128;
  const int tid = threadIdx.x;
  for (int i = tid; i < 16 * 512; i += 256)
    att[i] = attn_f[((size_t)b * 16 + (i >> 9)) * S_ + (i & 511)];
  __syncthreads();
  const int d = d0 + (tid & 127);
  const int sh = tid >> 7;
  float acc[16] = {};
  const float* hp = hidden + ((size_t)b * S_ + sh * 256) * D_ + d;
  for (int s = 0; s < 256; ++s) {
    float hv = hp[(size_t)s * D_];
    int si = sh * 256 + s;
#pragma unroll
    for (int kr = 0; kr < 16; ++kr) acc[kr] += att[kr * 512 + si] * hv;
  }
  __syncthreads();
  float* red = att;                 // reuse: [2][16][128]
#pragma unroll
  for (int kr = 0; kr < 16; ++kr) red[(sh * 16 + kr) * 128 + (tid & 127)] = acc[kr];
  __syncthreads();
  if (sh == 0) {
#pragma unroll
    for (int kr = 0; kr < 16; ++kr)
      out[((size_t)b * 16 + kr) * OUTC + 1024 + d] =
          red[kr * 128 + (tid & 127)] + red[(16 + kr) * 128 + (tid & 127)];
  }
}

// ---------------- MLP split-K GEMM (3-term partials), 3-buf pipeline ---------
__global__ __launch_bounds__(256) void mlp_gemm_kernel(
    const u16* __restrict__ Ah, const u16* __restrict__ Al, int a_br_stride,
    const u16* __restrict__ B0h, const u16* __restrict__ B0l,
    const u16* __restrict__ B1h, const u16* __restrict__ B1l,
    float* __restrict__ P, int M) {
  __shared__ u16 Ash[3][64 * 32];
  __shared__ u16 Asl[3][64 * 32];
  __shared__ u16 Bsh[3][64 * 32];
  __shared__ u16 Bsl[3][64 * 32];
  const int tid = threadIdx.x;
  const int zz = blockIdx.z;
  const int br = zz >> 2, ks = zz & 3;
  const u16* Ah_ = Ah + (size_t)br * a_br_stride;
  const u16* Al_ = Al + (size_t)br * a_br_stride;
  const u16* Bh = br ? B1h : B0h;
  const u16* Bl = br ? B1l : B0l;
  const int bm = blockIdx.y * 64, bn = blockIdx.x * 64;
  const int wave = tid >> 6, lane = tid & 63;
  const int wm = (wave >> 1) * 32, wn = (wave & 1) * 32;
  f32x4 acc[2][2] = {};
  const int fr = lane & 15;
  const int cc = lane >> 4;

  int lrow, cu;
  stage_map(wave, lane, 0, lrow, cu);
  int ga = bm + lrow;
  if (ga >= M) ga = M - 1;                  // clamp; OOB rows unused in epilogue
  const u16* ahsrc = Ah_ + (size_t)ga * D_ + cu;
  const u16* alsrc = Al_ + (size_t)ga * D_ + cu;
  const u16* bhsrc = Bh + (size_t)(bn + lrow) * D_ + cu;
  const u16* blsrc = Bl + (size_t)(bn + lrow) * D_ + cu;
  const int doff = wave * 64 * 8;
  int aoff[2], boff[2];
#pragma unroll
  for (int m = 0; m < 2; ++m) aoff[m] = swzidx(wm + m * 16 + fr, cc);
#pragma unroll
  for (int n = 0; n < 2; ++n) boff[n] = swzidx(wn + n * 16 + fr, cc);

  auto STAGE = [&](int buf, int k0) {
    gl16(ahsrc + k0, &Ash[buf][doff]);
    gl16(alsrc + k0, &Asl[buf][doff]);
    gl16(bhsrc + k0, &Bsh[buf][doff]);
    gl16(blsrc + k0, &Bsl[buf][doff]);
  };
  const int kbeg = ks * 256;
  const int NK = 8;                         // 256/32
  STAGE(0, kbeg);
  STAGE(1, kbeg + 32);
  for (int j = 0; j < NK; ++j) {
    if (j + 1 < NK) asm volatile("s_waitcnt vmcnt(4)" ::: "memory");
    else            asm volatile("s_waitcnt vmcnt(0)" ::: "memory");
    __builtin_amdgcn_s_barrier();
    if (j + 2 < NK) STAGE((j + 2) % 3, kbeg + (j + 2) * 32);
    const int cur = j % 3;
    bf16x8 afh[2], afl[2], bfh[2], bfl[2];
#pragma unroll
    for (int m = 0; m < 2; ++m) {
      afh[m] = *reinterpret_cast<const bf16x8*>(&Ash[cur][aoff[m]]);
      afl[m] = *reinterpret_cast<const bf16x8*>(&Asl[cur][aoff[m]]);
    }
#pragma unroll
    for (int n = 0; n < 2; ++n) {
      bfh[n] = *reinterpret_cast<const bf16x8*>(&Bsh[cur][boff[n]]);
      bfl[n] = *reinterpret_cast<const bf16x8*>(&Bsl[cur][boff[n]]);
    }
#pragma unroll
    for (int m = 0; m < 2; ++m)
#pragma unroll
      for (int n = 0; n < 2; ++n) {
        acc[m][n] = __builtin_amdgcn_mfma_f32_16x16x32_bf16(afh[m], bfh[n], acc[m][n], 0, 0, 0);
        acc[m][n] = __builtin_amdgcn_mfma_f32_16x16x32_bf16(afh[m], bfl[n], acc[m][n], 0, 0, 0);
        acc[m][n] = __builtin_amdgcn_mfma_f32_16x16x32_bf16(afl[m], bfh[n], acc[m][n], 0, 0, 0);
      }
  }
  const int ci = lane & 15;
  const int r0 = (lane >> 4) * 4;
#pragma unroll
  for (int m = 0; m < 2; ++m)
#pragma unroll
    for (int n = 0; n < 2; ++n) {
      int col = bn + wn + n * 16 + ci;
#pragma unroll
      for (int r = 0; r < 4; ++r) {
        int row = bm + wm + m * 16 + r0 + r;
        if (row < M)
          P[((size_t)zz * MROWS + row) * D_ + col] = acc[m][n][r];
      }
    }
}

// ---------------- MLP reduce ----------------
__global__ __launch_bounds__(256) void mlp_reduce_kernel(
    const float* __restrict__ P,
    const float* __restrict__ bias0, const float* __restrict__ bias1,
    u16* __restrict__ Oh, u16* __restrict__ Ol,
    float* __restrict__ Cf,
    int mode) {
  int i = blockIdx.x * 256 + threadIdx.x;
  int e = i * 4;
  const int per_br = MROWS * D_;
  int br = e / per_br;
  int rem = e - br * per_br;
  int row = rem >> 10;
  int col = rem & 1023;
  float4 s = {0.f, 0.f, 0.f, 0.f};
#pragma unroll
  for (int ks = 0; ks < 4; ++ks) {
    float4 v = *reinterpret_cast<const float4*>(
        P + ((size_t)(br * 4 + ks) * MROWS + row) * D_ + col);
    s.x += v.x; s.y += v.y; s.z += v.z; s.w += v.w;
  }
  const float* bias = br ? bias1 : bias0;
  s.x += bias[col]; s.y += bias[col + 1]; s.z += bias[col + 2]; s.w += bias[col + 3];
  if (mode == 0) {
    float a[4] = {tanhf(s.x), tanhf(s.y), tanhf(s.z), tanhf(s.w)};
    size_t o = (size_t)br * per_br + (size_t)row * D_ + col;
#pragma unroll
    for (int j = 0; j < 4; ++j) {
      u16 h = f2b(a[j]);
      Oh[o + j] = h;
      Ol[o + j] = f2b(a[j] - b2f(h));
    }
  } else {
    *reinterpret_cast<float4*>(Cf + (size_t)row * 2048 + br * 1024 + col) = s;
  }
}

// ---------------- labels ----------------
__global__ __launch_bounds__(64) void labels_kernel(
    const float* __restrict__ s_cat, const float* __restrict__ t_cat,
    const int* __restrict__ src_ids, float* __restrict__ out) {
  int bk = blockIdx.x, lane = threadIdx.x;
  const float* srow = s_cat + (size_t)bk * 2048;
  float np = 0.f;
  float dots[16], tsq[16];
#pragma unroll
  for (int t = 0; t < 16; ++t) { dots[t] = 0.f; tsq[t] = 0.f; }
  for (int j = lane; j < 2048; j += 64) {
    float sv = srow[j];
    np += sv * sv;
#pragma unroll
    for (int t = 0; t < 16; ++t) {
      float tv = t_cat[t * 2048 + j];
      dots[t] += sv * tv;
      tsq[t] += tv * tv;
    }
  }
  np = wredsum(np);
#pragma unroll
  for (int t = 0; t < 16; ++t) { dots[t] = wredsum(dots[t]); tsq[t] = wredsum(tsq[t]); }
  float sn = fmaxf(sqrtf(np), 1e-8f);
  float ssum = 0.f;
  float sims[16];
#pragma unroll
  for (int t = 0; t < 16; ++t) {
    float tn = fmaxf(sqrtf(tsq[t]), 1e-8f);
    sims[t] = dots[t] / (sn * tn);
    ssum += sims[t];
  }
  float scale = 0.9f / ssum;
  if (lane < 16) {
    out[(size_t)bk * OUTC + 2064 + lane] = sims[lane] * scale;
  } else if (lane < 32) {
    int t2 = lane - 16;
    out[(size_t)bk * OUTC + 2048 + t2] = (src_ids[bk] == t2) ? 0.1f : 0.f;
  }
}

// =======================================================================
extern "C" void kernel_launch(void* const* d_in, const int* in_sizes, int n_in,
                              void* d_out, int out_size, void* d_ws, size_t ws_size,
                              hipStream_t stream) {
  const float* hidden    = (const float*)d_in[0];
  const int*   span_idx  = (const int*)d_in[1];
  const float* span_mask = (const float*)d_in[2];
  const int*   span_start= (const int*)d_in[3];
  const int*   span_end  = (const int*)d_in[4];
  const int*   length    = (const int*)d_in[5];
  const float* slot_emb  = (const float*)d_in[6];
  const float* tgt       = (const float*)d_in[7];
  const int*   src_ids   = (const int*)d_in[8];
  const float* Wih_f = (const float*)d_in[9];
  const float* Whh_f = (const float*)d_in[10];
  const float* bih_f = (const float*)d_in[11];
  const float* bhh_f = (const float*)d_in[12];
  const float* Wih_b = (const float*)d_in[13];
  const float* Whh_b = (const float*)d_in[14];
  const float* bih_b = (const float*)d_in[15];
  const float* bhh_b = (const float*)d_in[16];
  const float* Wps1 = (const float*)d_in[17];
  const float* bps1 = (const float*)d_in[18];
  const float* Wps2 = (const float*)d_in[19];
  const float* bps2 = (const float*)d_in[20];
  const float* Wpc1 = (const float*)d_in[21];
  const float* bpc1 = (const float*)d_in[22];
  const float* Wpc2 = (const float*)d_in[23];
  const float* bpc2 = (const float*)d_in[24];
  float* out = (float*)d_out;

  char* p = (char*)d_ws;
  auto alloc = [&](size_t bytes) -> void* {
    void* r = (void*)p;
    p += (bytes + 255) & ~(size_t)255;
    return r;
  };
  // BIG1: G2 bf16 [L][NSEQ][4096] (64 MB), dead after recurrence -> P partials
  char*  BIG1  = (char*)alloc((size_t)XROWS * 4096 * 2);
  // BIG2: Hh/Hl bf16 splits of hidden (67.1 MB)
  char*  BIG2  = (char*)alloc((size_t)2 * B_ * S_ * D_ * 2);
  float* hst   = (float*)alloc((size_t)2 * NSEQ * H_ * 4);
  float* cst   = (float*)alloc((size_t)2 * NSEQ * H_ * 4);
  u16*   hbfA  = (u16*)alloc((size_t)2 * NSEQ * H_ * 2);
  u16*   hbfB  = (u16*)alloc((size_t)2 * NSEQ * H_ * 2);
  float* sf    = (float*)alloc((size_t)NSEQ * 1024 * 4);
  u16*   sfh   = (u16*)alloc((size_t)NSEQ * 1024 * 2);
  u16*   sfl   = (u16*)alloc((size_t)NSEQ * 1024 * 2);
  float* attn_f= (float*)alloc((size_t)NSEQ * S_ * 4);
  float* CAT   = (float*)alloc((size_t)MROWS * 2048 * 4);
  u16* Wih2_i = (u16*)alloc((size_t)2 * G4H * D_ * 2);
  u16* Whhf_i = (u16*)alloc((size_t)G4H * H_ * 2);
  u16* Whhb_i = (u16*)alloc((size_t)G4H * H_ * 2);
  float* bsumf = (float*)alloc(G4H * 4);
  float* bsumb = (float*)alloc(G4H * 4);
  u16* W1sh = (u16*)alloc((size_t)D_ * D_ * 2); u16* W1sl = (u16*)alloc((size_t)D_ * D_ * 2);
  u16* W2sh = (u16*)alloc((size_t)D_ * D_ * 2); u16* W2sl = (u16*)alloc((size_t)D_ * D_ * 2);
  u16* W1ch = (u16*)alloc((size_t)D_ * D_ * 2); u16* W1cl = (u16*)alloc((size_t)D_ * D_ * 2);
  u16* W2ch = (u16*)alloc((size_t)D_ * D_ * 2); u16* W2cl = (u16*)alloc((size_t)D_ * D_ * 2);
  u16* SEh = (u16*)alloc((size_t)MROWS * D_ * 2); u16* SEl = (u16*)alloc((size_t)MROWS * D_ * 2);
  u16* T1h = (u16*)alloc((size_t)2 * MROWS * D_ * 2);
  u16* T1l = (u16*)alloc((size_t)2 * MROWS * D_ * 2);

  // aliases
  u16*   G2 = (u16*)BIG1;
  float* P  = (float*)BIG1;             // after recurrence
  u16*   Hh = (u16*)BIG2;
  u16*   Hl = Hh + (size_t)B_ * S_ * D_;

  size_t need = (size_t)(p - (char*)d_ws);
  if (need > ws_size) {
    fprintf(stderr, "kernel_launch: ws too small, need %zu have %zu\n", need, ws_size);
    return;
  }

  auto split = [&](const float* src, u16* hi, u16* lo, int n) {
    split_kernel<<<(n + 255) / 256, 256, 0, stream>>>(src, hi, lo, n);
  };

  // weight prep
  icast_kernel<<<G4H, 256, 0, stream>>>(Wih_f, Wih2_i, D_);
  icast_kernel<<<G4H, 256, 0, stream>>>(Wih_b, Wih2_i + (size_t)G4H * D_, D_);
  icast_kernel<<<G4H, 256, 0, stream>>>(Whh_f, Whhf_i, H_);
  icast_kernel<<<G4H, 256, 0, stream>>>(Whh_b, Whhb_i, H_);
  bsum_kernel<<<8, 256, 0, stream>>>(bih_f, bhh_f, bsumf);
  bsum_kernel<<<8, 256, 0, stream>>>(bih_b, bhh_b, bsumb);
  {
    dim3 g((D_ * D_) / 256, 4);
    split4_kernel<<<g, 256, 0, stream>>>(Wps1, Wps2, Wpc1, Wpc2,
                                         W1sh, W1sl, W2sh, W2sl,
                                         W1ch, W1cl, W2ch, W2cl);
  }
  split(slot_emb, SEh, SEl, NSEQ * D_);
  split(tgt, SEh + (size_t)NSEQ * D_, SEl + (size_t)NSEQ * D_, NT_ * D_);

  // hidden hi/lo split (Hh feeds gathered big GEMM + attn)
  hsplit_kernel<<<(B_ * S_ * D_) / (4 * 256), 256, 0, stream>>>(hidden, Hh, Hl);

  // ---- big input GEMM (gather fused, swizzled, 3-buf pipeline) ----
  {
    dim3 g(4096 / 128, XROWS / 128);
    big_gemm_kernel<<<g, 256, 0, stream>>>(Hh, span_idx, Wih2_i, G2);
  }

  // ---- bi-LSTM recurrence ----
  for (int t = 0; t < L_; ++t) {
    const u16* hin = (t & 1) ? hbfA : hbfB;
    u16* hout = (t & 1) ? hbfB : hbfA;
    dim3 g(G4H / 64, NSEQ / 64, 2);
    lstm_step_kernel<<<g, 256, 0, stream>>>(hin, Whhf_i, Whhb_i, G2, bsumf, bsumb,
                                            span_mask, hst, cst, hout, sf,
                                            t, t == 0 ? 1 : 0);
  }

  // ---- slot_feats out + splits ----
  copy_sf_split_kernel<<<NSEQ, 256, 0, stream>>>(sf, out, sfh, sfl);

  // ---- attention (3-term MFMA, f32 scores) + context (exact f32) ----
  {
    dim3 g(B_, S_ / 128);
    attn_mfma_kernel<<<g, 256, 0, stream>>>(sfh, sfl, Hh, Hl,
                                            span_start, span_end, length, attn_f);
  }
  {
    dim3 g(B_, D_ / 128);
    ctx_f32_kernel<<<g, 256, 0, stream>>>(attn_f, hidden, out);
  }

  // ---- MLPs: split-K x 2 branches; G2 dead -> P aliases BIG1 ----
  {
    dim3 g(D_ / 64, (MROWS + 63) / 64, 8);
    dim3 rg((2 * MROWS * D_) / (4 * 256));
    mlp_gemm_kernel<<<g, 256, 0, stream>>>(SEh, SEl, 0, W1sh, W1sl, W1ch, W1cl, P, MROWS);
    mlp_reduce_kernel<<<rg, 256, 0, stream>>>(P, bps1, bpc1, T1h, T1l, nullptr, 0);
    mlp_gemm_kernel<<<g, 256, 0, stream>>>(T1h, T1l, MROWS * D_, W2sh, W2sl, W2ch, W2cl, P, MROWS);
    mlp_reduce_kernel<<<rg, 256, 0, stream>>>(P, bps2, bpc2, nullptr, nullptr, CAT, 1);
  }

  // ---- labels ----
  const float* t_cat = CAT + (size_t)NSEQ * 2048;
  labels_kernel<<<NSEQ, 64, 0, stream>>>(CAT, t_cat, src_ids, out);
}

// Round 8
// 639.895 us; speedup vs baseline: 1.0356x; 1.0356x over previous
//
#include <hip/hip_runtime.h>
#include <cstdio>

#define B_ 32
#define S_ 512
#define D_ 1024
#define H_ 512
#define K_ 16
#define L_ 16
#define NT_ 16
#define NSEQ 512      // B*K
#define XROWS 8192    // NSEQ*L
#define G4H 2048      // 4*H
#define OUTC 2080
#define MROWS 528     // NSEQ + NT

typedef unsigned short u16;
typedef __bf16 bf16x8 __attribute__((ext_vector_type(8)));
typedef float f32x4 __attribute__((ext_vector_type(4)));

__device__ inline u16 f2b(float f) {
  union { float f; unsigned u; } x; x.f = f;
  unsigned r = x.u + 0x7FFFu + ((x.u >> 16) & 1u);
  return (u16)(r >> 16);
}
__device__ inline float b2f(u16 h) {
  union { unsigned u; float f; } c; c.u = ((unsigned)h) << 16;
  return c.f;
}
__device__ inline float sigf(float x) { return 1.0f / (1.0f + expf(-x)); }
__device__ inline float wredsum(float v) {
#pragma unroll
  for (int off = 32; off > 0; off >>= 1) v += __shfl_xor(v, off);
  return v;
}
// async global->LDS, 16B/lane; dest = wave-uniform base + lane*16 (linear)
__device__ inline void gl16(const u16* g, u16* l) {
  __builtin_amdgcn_global_load_lds(
      (const __attribute__((address_space(1))) unsigned int*)g,
      (__attribute__((address_space(3))) unsigned int*)l, 16, 0, 0);
}

// ---------------- split f32 -> hi+lo bf16 ----------------
__global__ __launch_bounds__(256) void split_kernel(const float* __restrict__ in,
                                                    u16* __restrict__ hi,
                                                    u16* __restrict__ lo, int n) {
  int i = blockIdx.x * 256 + threadIdx.x;
  if (i >= n) return;
  float x = in[i];
  u16 h = f2b(x);
  hi[i] = h;
  lo[i] = f2b(x - b2f(h));
}

// slot_emb + tgt -> SEh/SEl in one launch (contiguous dest)
__global__ __launch_bounds__(256) void sesplit_kernel(const float* __restrict__ se,
                                                      const float* __restrict__ tg,
                                                      u16* __restrict__ hi,
                                                      u16* __restrict__ lo) {
  int i = blockIdx.x * 256 + threadIdx.x;    // < MROWS*D
  float x = (i < NSEQ * D_) ? se[i] : tg[i - NSEQ * D_];
  u16 h = f2b(x);
  hi[i] = h;
  lo[i] = f2b(x - b2f(h));
}

// 4 MLP weights in one launch: blockIdx.y selects
__global__ __launch_bounds__(256) void split4_kernel(
    const float* __restrict__ s0, const float* __restrict__ s1,
    const float* __restrict__ s2, const float* __restrict__ s3,
    u16* __restrict__ h0, u16* __restrict__ l0,
    u16* __restrict__ h1, u16* __restrict__ l1,
    u16* __restrict__ h2, u16* __restrict__ l2,
    u16* __restrict__ h3, u16* __restrict__ l3) {
  const float* src = blockIdx.y == 0 ? s0 : blockIdx.y == 1 ? s1 : blockIdx.y == 2 ? s2 : s3;
  u16* hi = blockIdx.y == 0 ? h0 : blockIdx.y == 1 ? h1 : blockIdx.y == 2 ? h2 : h3;
  u16* lo = blockIdx.y == 0 ? l0 : blockIdx.y == 1 ? l1 : blockIdx.y == 2 ? l2 : l3;
  int i = blockIdx.x * 256 + threadIdx.x;
  float x = src[i];
  u16 h = f2b(x);
  hi[i] = h;
  lo[i] = f2b(x - b2f(h));
}

__global__ __launch_bounds__(256) void hsplit_kernel(const float* __restrict__ in,
                                                     u16* __restrict__ hi,
                                                     u16* __restrict__ lo) {
  size_t i = ((size_t)blockIdx.x * 256 + threadIdx.x) * 4;
  float4 v = *reinterpret_cast<const float4*>(in + i);
  float a[4] = {v.x, v.y, v.z, v.w};
#pragma unroll
  for (int j = 0; j < 4; ++j) {
    u16 h = f2b(a[j]);
    hi[i + j] = h;
    lo[i + j] = f2b(a[j] - b2f(h));
  }
}

// interleave-cast all 4 LSTM weights: y = 0: Wih_f, 1: Wih_b, 2: Whh_f, 3: Whh_b
__global__ __launch_bounds__(256) void wprep_kernel(
    const float* __restrict__ Wihf, const float* __restrict__ Wihb,
    const float* __restrict__ Whhf, const float* __restrict__ Whhb,
    u16* __restrict__ Wih2_i, u16* __restrict__ Whhf_i, u16* __restrict__ Whhb_i) {
  int y = blockIdx.y;
  const float* W = y == 0 ? Wihf : y == 1 ? Wihb : y == 2 ? Whhf : Whhb;
  int Kd = (y < 2) ? D_ : H_;
  u16* dst = y == 0 ? Wih2_i : y == 1 ? (Wih2_i + (size_t)G4H * D_) : y == 2 ? Whhf_i : Whhb_i;
  int rp = blockIdx.x;
  int j = rp >> 2, g = rp & 3;
  const float* src = W + ((size_t)(g * H_ + j)) * Kd;
  u16* d = dst + (size_t)rp * Kd;
  for (int k = threadIdx.x; k < Kd; k += 256) d[k] = f2b(src[k]);
}

// both interleaved biases in one launch
__global__ __launch_bounds__(256) void bsum2_kernel(
    const float* __restrict__ bihf, const float* __restrict__ bhhf,
    const float* __restrict__ bihb, const float* __restrict__ bhhb,
    float* __restrict__ bsumf, float* __restrict__ bsumb) {
  int i = blockIdx.x * 256 + threadIdx.x;    // < 2*G4H
  int dir = i >> 11;
  int rp = i & (G4H - 1);
  int j = rp >> 2, g = rp & 3;
  const float* bi = dir ? bihb : bihf;
  const float* bh = dir ? bhhb : bhhf;
  float v = bi[g * H_ + j] + bh[g * H_ + j];
  (dir ? bsumb : bsumf)[rp] = v;
}

// ---- big input GEMM, gather fused, linear LDS, single-buf (proven 95.6us) ----
// M-row' = t*NSEQ + seq: contiguous t-major G2 store AND contiguous step reads.
__global__ __launch_bounds__(256) void big_gemm_kernel(
    const u16* __restrict__ Hh, const int* __restrict__ span_idx,
    const u16* __restrict__ Wih2, u16* __restrict__ G2) {
  __shared__ u16 As[128 * 32];
  __shared__ u16 Bs[128 * 32];
  const int tid = threadIdx.x;
  const int bn = blockIdx.x * 128, bm = blockIdx.y * 128;
  const int wave = tid >> 6, lane = tid & 63;
  const int wm = (wave >> 1) * 64, wn = (wave & 1) * 64;
  const int fr = lane & 15;
  const int kg = (lane >> 4) * 8;

  const u16* asrc[2];
  const u16* bsrc[2];
  u16* adst[2];
  u16* bdst[2];
#pragma unroll
  for (int j = 0; j < 2; ++j) {
    int c = tid + 256 * j;
    int gr = bm + (c >> 2);                 // row' = t*NSEQ + seq
    int t = gr >> 9;
    int seq = gr & 511;
    int b = seq >> 4;
    int sidx = span_idx[seq * L_ + t];
    asrc[j] = Hh + ((size_t)(b * S_ + sidx)) * D_ + (c & 3) * 8;
    bsrc[j] = Wih2 + (size_t)(bn + (c >> 2)) * D_ + (c & 3) * 8;
    int ub = (wave * 64 + 256 * j) * 8;
    adst[j] = As + ub;
    bdst[j] = Bs + ub;
  }

  f32x4 acc[4][4] = {};
  for (int k0 = 0; k0 < D_; k0 += 32) {
    gl16(asrc[0] + k0, adst[0]);
    gl16(asrc[1] + k0, adst[1]);
    gl16(bsrc[0] + k0, bdst[0]);
    gl16(bsrc[1] + k0, bdst[1]);
    __syncthreads();
    bf16x8 af[4], bfr[4];
#pragma unroll
    for (int m = 0; m < 4; ++m)
      af[m] = *reinterpret_cast<const bf16x8*>(&As[(wm + m * 16 + fr) * 32 + kg]);
#pragma unroll
    for (int n = 0; n < 4; ++n)
      bfr[n] = *reinterpret_cast<const bf16x8*>(&Bs[(wn + n * 16 + fr) * 32 + kg]);
#pragma unroll
    for (int m = 0; m < 4; ++m)
#pragma unroll
      for (int n = 0; n < 4; ++n)
        acc[m][n] = __builtin_amdgcn_mfma_f32_16x16x32_bf16(af[m], bfr[n], acc[m][n], 0, 0, 0);
    __syncthreads();
  }
  const int ci = lane & 15;
  const int r0 = (lane >> 4) * 4;
#pragma unroll
  for (int m = 0; m < 4; ++m)
#pragma unroll
    for (int n = 0; n < 4; ++n) {
      int col = bn + wn + n * 16 + ci;
#pragma unroll
      for (int r = 0; r < 4; ++r) {
        int row = bm + wm + m * 16 + r0 + r;    // t-major row', contiguous
        G2[(size_t)row * 4096 + col] = f2b(acc[m][n][r]);
      }
    }
}

// ---------------- fused recurrent GEMM + LSTM gate step (both dirs via z) ------
// last==1: also write slot_feats to out + sfh/sfl splits (replaces copy_sf).
__global__ __launch_bounds__(256) void lstm_step_kernel(
    const u16* __restrict__ hbf_in,
    const u16* __restrict__ Whhf, const u16* __restrict__ Whhb,
    const u16* __restrict__ G2,
    const float* __restrict__ bsumf, const float* __restrict__ bsumb,
    const float* __restrict__ mask,
    float* __restrict__ hst, float* __restrict__ cst,
    u16* __restrict__ hbf_out,
    float* __restrict__ sf,
    float* __restrict__ out, u16* __restrict__ sfh, u16* __restrict__ sfl,
    int t, int first, int last) {
  __shared__ u16 As[64 * 32];
  __shared__ u16 Bs[64 * 32];
  const int tid = threadIdx.x;
  const int bz = blockIdx.z;
  const int treal = bz ? (L_ - 1 - t) : t;
  const u16* Whh = bz ? Whhb : Whhf;
  const float* bsum = bz ? bsumb : bsumf;
  const size_t sofs = (size_t)bz * NSEQ * H_;
  const int bm = blockIdx.y * 64, bn = blockIdx.x * 64;
  const int wave = tid >> 6, lane = tid & 63;
  const int wm = (wave >> 1) * 32, wn = (wave & 1) * 32;
  f32x4 acc[2][2] = {};
  const int fr = lane & 15;
  const int kg = (lane >> 4) * 8;

  if (!first) {
    const int c = tid;
    const u16* asrc = hbf_in + sofs + (size_t)(bm + (c >> 2)) * H_ + (c & 3) * 8;
    const u16* bsrc = Whh + (size_t)(bn + (c >> 2)) * H_ + (c & 3) * 8;
    u16* adst = As + wave * 512;
    u16* bdst = Bs + wave * 512;
    for (int k0 = 0; k0 < H_; k0 += 32) {
      gl16(asrc + k0, adst);
      gl16(bsrc + k0, bdst);
      __syncthreads();
      bf16x8 af[2], bfr[2];
#pragma unroll
      for (int m = 0; m < 2; ++m)
        af[m] = *reinterpret_cast<const bf16x8*>(&As[(wm + m * 16 + fr) * 32 + kg]);
#pragma unroll
      for (int n = 0; n < 2; ++n)
        bfr[n] = *reinterpret_cast<const bf16x8*>(&Bs[(wn + n * 16 + fr) * 32 + kg]);
#pragma unroll
      for (int m = 0; m < 2; ++m)
#pragma unroll
        for (int n = 0; n < 2; ++n)
          acc[m][n] = __builtin_amdgcn_mfma_f32_16x16x32_bf16(af[m], bfr[n], acc[m][n], 0, 0, 0);
      __syncthreads();
    }
  }

  const int ci = lane & 15;
  const int r0 = (lane >> 4) * 4;
  const int q = lane & 3;
#pragma unroll
  for (int m = 0; m < 2; ++m)
#pragma unroll
    for (int n = 0; n < 2; ++n) {
      int c = bn + wn + n * 16 + ci;
      int rowbase = bm + wm + m * 16 + r0;
      float val[4];
#pragma unroll
      for (int r = 0; r < 4; ++r) {
        int nrow = rowbase + r;
        // t-major G2: contiguous slab per treal
        float g2 = b2f(G2[((size_t)treal * NSEQ + nrow) * 4096 + (size_t)bz * 2048 + c]);
        val[r] = acc[m][n][r] + g2 + bsum[c];
      }
      float x1[4], x2[4], x3[4];
#pragma unroll
      for (int r = 0; r < 4; ++r) {
        x1[r] = __shfl_xor(val[r], 1);
        x2[r] = __shfl_xor(val[r], 2);
        x3[r] = __shfl_xor(x1[r], 2);
      }
      if (q == 0) {
        int j = c >> 2;
#pragma unroll
        for (int r = 0; r < 4; ++r) {
          int nrow = rowbase + r;
          float gi = val[r], gf = x1[r], gg = x2[r], go = x3[r];
          float mv = mask[nrow * L_ + treal];
          size_t sidx = sofs + (size_t)nrow * H_ + j;
          float co = first ? 0.f : cst[sidx];
          float ho = first ? 0.f : hst[sidx];
          float cn = sigf(gf) * co + sigf(gi) * tanhf(gg);
          float hn = sigf(go) * tanhf(cn);
          float hnew = mv * hn + (1.f - mv) * ho;
          float cnew = mv * cn + (1.f - mv) * co;
          hst[sidx] = hnew;
          cst[sidx] = cnew;
          hbf_out[sidx] = f2b(hnew);
          size_t fidx = (size_t)nrow * 1024 + bz * 512 + j;
          float contrib = hnew * mv;
          float snew = first ? contrib : sf[fidx] + contrib;
          sf[fidx] = snew;
          if (last) {
            out[(size_t)nrow * OUTC + bz * 512 + j] = snew;
            u16 hh = f2b(snew);
            sfh[fidx] = hh;
            sfl[fidx] = f2b(snew - b2f(hh));
          }
        }
      }
    }
}

// ---------------- attn = sf . hidden^T (3-term), masked, f32 out ----------------
__global__ __launch_bounds__(256) void attn_mfma_kernel(
    const u16* __restrict__ sfh, const u16* __restrict__ sfl,
    const u16* __restrict__ Hh, const u16* __restrict__ Hl,
    const int* __restrict__ sstart, const int* __restrict__ send,
    const int* __restrict__ len,
    float* __restrict__ attn_f) {
  __shared__ u16 Bh[128 * 32];
  __shared__ u16 Bl[128 * 32];
  const int b = blockIdx.x;
  const int s0 = blockIdx.y * 128;
  const int tid = threadIdx.x;
  const int wave = tid >> 6, lane = tid & 63;
  const int fr = lane & 15;
  const int kg = (lane >> 4) * 8;
  f32x4 acc[2] = {};

  const u16* hsrc[2];
  const u16* lsrc[2];
  u16* hdst[2];
  u16* ldst[2];
#pragma unroll
  for (int j = 0; j < 2; ++j) {
    int c = tid + 256 * j;
    size_t goff = ((size_t)b * S_ + s0 + (c >> 2)) * D_ + (c & 3) * 8;
    hsrc[j] = Hh + goff;
    lsrc[j] = Hl + goff;
    int ub = (wave * 64 + 256 * j) * 8;
    hdst[j] = Bh + ub;
    ldst[j] = Bl + ub;
  }

  for (int k0 = 0; k0 < D_; k0 += 32) {
    gl16(hsrc[0] + k0, hdst[0]);
    gl16(hsrc[1] + k0, hdst[1]);
    gl16(lsrc[0] + k0, ldst[0]);
    gl16(lsrc[1] + k0, ldst[1]);
    __syncthreads();
    size_t aoff = ((size_t)b * 16 + fr) * D_ + k0 + kg;
    bf16x8 ah = *reinterpret_cast<const bf16x8*>(sfh + aoff);
    bf16x8 al = *reinterpret_cast<const bf16x8*>(sfl + aoff);
#pragma unroll
    for (int nt = 0; nt < 2; ++nt) {
      bf16x8 bh = *reinterpret_cast<const bf16x8*>(&Bh[(wave * 32 + nt * 16 + fr) * 32 + kg]);
      bf16x8 bl = *reinterpret_cast<const bf16x8*>(&Bl[(wave * 32 + nt * 16 + fr) * 32 + kg]);
      acc[nt] = __builtin_amdgcn_mfma_f32_16x16x32_bf16(ah, bh, acc[nt], 0, 0, 0);
      acc[nt] = __builtin_amdgcn_mfma_f32_16x16x32_bf16(ah, bl, acc[nt], 0, 0, 0);
      acc[nt] = __builtin_amdgcn_mfma_f32_16x16x32_bf16(al, bh, acc[nt], 0, 0, 0);
    }
    __syncthreads();
  }
  const int ln = len[b];
#pragma unroll
  for (int nt = 0; nt < 2; ++nt) {
    int s = s0 + wave * 32 + nt * 16 + (lane & 15);
#pragma unroll
    for (int r = 0; r < 4; ++r) {
      int krow = (lane >> 4) * 4 + r;
      int bk = b * 16 + krow;
      int st = sstart[bk], en = send[bk];
      bool cm = (s < st) || ((s > en) && (s < ln));
      attn_f[(size_t)bk * S_ + s] = cm ? acc[nt][r] : 0.f;
    }
  }
}

// ---------------- context (exact f32): out[.,1024+d] = sum_s attn*hidden ----
__global__ __launch_bounds__(256) void ctx_f32_kernel(
    const float* __restrict__ attn_f, const float* __restrict__ hidden,
    float* __restrict__ out) {
  __shared__ float att[16 * 512];   // 32 KB
  const int b = blockIdx.x;
  const int d0 = blockIdx.y * 128;
  const int tid = threadIdx.x;
  for (int i = tid; i < 16 * 512; i += 256)
    att[i] = attn_f[((size_t)b * 16 + (i >> 9)) * S_ + (i & 511)];
  __syncthreads();
  const int d = d0 + (tid & 127);
  const int sh = tid >> 7;
  float acc[16] = {};
  const float* hp = hidden + ((size_t)b * S_ + sh * 256) * D_ + d;
  for (int s = 0; s < 256; ++s) {
    float hv = hp[(size_t)s * D_];
    int si = sh * 256 + s;
#pragma unroll
    for (int kr = 0; kr < 16; ++kr) acc[kr] += att[kr * 512 + si] * hv;
  }
  __syncthreads();
  float* red = att;                 // reuse: [2][16][128]
#pragma unroll
  for (int kr = 0; kr < 16; ++kr) red[(sh * 16 + kr) * 128 + (tid & 127)] = acc[kr];
  __syncthreads();
  if (sh == 0) {
#pragma unroll
    for (int kr = 0; kr < 16; ++kr)
      out[((size_t)b * 16 + kr) * OUTC + 1024 + d] =
          red[kr * 128 + (tid & 127)] + red[(16 + kr) * 128 + (tid & 127)];
  }
}

// ---------------- MLP split-K GEMM (3-term partials), single-buf linear ---------
__global__ __launch_bounds__(256) void mlp_gemm_kernel(
    const u16* __restrict__ Ah, const u16* __restrict__ Al, int a_br_stride,
    const u16* __restrict__ B0h, const u16* __restrict__ B0l,
    const u16* __restrict__ B1h, const u16* __restrict__ B1l,
    float* __restrict__ P, int M) {
  __shared__ u16 Ash[64 * 32];
  __shared__ u16 Asl[64 * 32];
  __shared__ u16 Bsh[64 * 32];
  __shared__ u16 Bsl[64 * 32];
  const int tid = threadIdx.x;
  const int zz = blockIdx.z;
  const int br = zz >> 2, ks = zz & 3;
  const u16* Ah_ = Ah + (size_t)br * a_br_stride;
  const u16* Al_ = Al + (size_t)br * a_br_stride;
  const u16* Bh = br ? B1h : B0h;
  const u16* Bl = br ? B1l : B0l;
  const int bm = blockIdx.y * 64, bn = blockIdx.x * 64;
  const int wave = tid >> 6, lane = tid & 63;
  const int wm = (wave >> 1) * 32, wn = (wave & 1) * 32;
  f32x4 acc[2][2] = {};
  const int fr = lane & 15;
  const int kg = (lane >> 4) * 8;

  const int c = tid;
  int ga = bm + (c >> 2);
  if (ga >= M) ga = M - 1;                  // clamp; OOB rows unused in epilogue
  const u16* ahsrc = Ah_ + (size_t)ga * D_ + (c & 3) * 8;
  const u16* alsrc = Al_ + (size_t)ga * D_ + (c & 3) * 8;
  const u16* bhsrc = Bh + (size_t)(bn + (c >> 2)) * D_ + (c & 3) * 8;
  const u16* blsrc = Bl + (size_t)(bn + (c >> 2)) * D_ + (c & 3) * 8;
  u16* d0 = Ash + wave * 512;
  u16* d1 = Asl + wave * 512;
  u16* d2 = Bsh + wave * 512;
  u16* d3 = Bsl + wave * 512;

  const int kbeg = ks * 256;
  for (int k0 = kbeg; k0 < kbeg + 256; k0 += 32) {
    gl16(ahsrc + k0, d0);
    gl16(alsrc + k0, d1);
    gl16(bhsrc + k0, d2);
    gl16(blsrc + k0, d3);
    __syncthreads();
    bf16x8 afh[2], afl[2], bfh[2], bfl[2];
#pragma unroll
    for (int m = 0; m < 2; ++m) {
      afh[m] = *reinterpret_cast<const bf16x8*>(&Ash[(wm + m * 16 + fr) * 32 + kg]);
      afl[m] = *reinterpret_cast<const bf16x8*>(&Asl[(wm + m * 16 + fr) * 32 + kg]);
    }
#pragma unroll
    for (int n = 0; n < 2; ++n) {
      bfh[n] = *reinterpret_cast<const bf16x8*>(&Bsh[(wn + n * 16 + fr) * 32 + kg]);
      bfl[n] = *reinterpret_cast<const bf16x8*>(&Bsl[(wn + n * 16 + fr) * 32 + kg]);
    }
#pragma unroll
    for (int m = 0; m < 2; ++m)
#pragma unroll
      for (int n = 0; n < 2; ++n) {
        acc[m][n] = __builtin_amdgcn_mfma_f32_16x16x32_bf16(afh[m], bfh[n], acc[m][n], 0, 0, 0);
        acc[m][n] = __builtin_amdgcn_mfma_f32_16x16x32_bf16(afh[m], bfl[n], acc[m][n], 0, 0, 0);
        acc[m][n] = __builtin_amdgcn_mfma_f32_16x16x32_bf16(afl[m], bfh[n], acc[m][n], 0, 0, 0);
      }
    __syncthreads();
  }
  const int ci = lane & 15;
  const int r0 = (lane >> 4) * 4;
#pragma unroll
  for (int m = 0; m < 2; ++m)
#pragma unroll
    for (int n = 0; n < 2; ++n) {
      int col = bn + wn + n * 16 + ci;
#pragma unroll
      for (int r = 0; r < 4; ++r) {
        int row = bm + wm + m * 16 + r0 + r;
        if (row < M)
          P[((size_t)zz * MROWS + row) * D_ + col] = acc[m][n][r];
      }
    }
}

// ---------------- MLP reduce ----------------
__global__ __launch_bounds__(256) void mlp_reduce_kernel(
    const float* __restrict__ P,
    const float* __restrict__ bias0, const float* __restrict__ bias1,
    u16* __restrict__ Oh, u16* __restrict__ Ol,
    float* __restrict__ Cf,
    int mode) {
  int i = blockIdx.x * 256 + threadIdx.x;
  int e = i * 4;
  const int per_br = MROWS * D_;
  int br = e / per_br;
  int rem = e - br * per_br;
  int row = rem >> 10;
  int col = rem & 1023;
  float4 s = {0.f, 0.f, 0.f, 0.f};
#pragma unroll
  for (int ks = 0; ks < 4; ++ks) {
    float4 v = *reinterpret_cast<const float4*>(
        P + ((size_t)(br * 4 + ks) * MROWS + row) * D_ + col);
    s.x += v.x; s.y += v.y; s.z += v.z; s.w += v.w;
  }
  const float* bias = br ? bias1 : bias0;
  s.x += bias[col]; s.y += bias[col + 1]; s.z += bias[col + 2]; s.w += bias[col + 3];
  if (mode == 0) {
    float a[4] = {tanhf(s.x), tanhf(s.y), tanhf(s.z), tanhf(s.w)};
    size_t o = (size_t)br * per_br + (size_t)row * D_ + col;
#pragma unroll
    for (int j = 0; j < 4; ++j) {
      u16 h = f2b(a[j]);
      Oh[o + j] = h;
      Ol[o + j] = f2b(a[j] - b2f(h));
    }
  } else {
    *reinterpret_cast<float4*>(Cf + (size_t)row * 2048 + br * 1024 + col) = s;
  }
}

// ---------------- labels ----------------
__global__ __launch_bounds__(64) void labels_kernel(
    const float* __restrict__ s_cat, const float* __restrict__ t_cat,
    const int* __restrict__ src_ids, float* __restrict__ out) {
  int bk = blockIdx.x, lane = threadIdx.x;
  const float* srow = s_cat + (size_t)bk * 2048;
  float np = 0.f;
  float dots[16], tsq[16];
#pragma unroll
  for (int t = 0; t < 16; ++t) { dots[t] = 0.f; tsq[t] = 0.f; }
  for (int j = lane; j < 2048; j += 64) {
    float sv = srow[j];
    np += sv * sv;
#pragma unroll
    for (int t = 0; t < 16; ++t) {
      float tv = t_cat[t * 2048 + j];
      dots[t] += sv * tv;
      tsq[t] += tv * tv;
    }
  }
  np = wredsum(np);
#pragma unroll
  for (int t = 0; t < 16; ++t) { dots[t] = wredsum(dots[t]); tsq[t] = wredsum(tsq[t]); }
  float sn = fmaxf(sqrtf(np), 1e-8f);
  float ssum = 0.f;
  float sims[16];
#pragma unroll
  for (int t = 0; t < 16; ++t) {
    float tn = fmaxf(sqrtf(tsq[t]), 1e-8f);
    sims[t] = dots[t] / (sn * tn);
    ssum += sims[t];
  }
  float scale = 0.9f / ssum;
  if (lane < 16) {
    out[(size_t)bk * OUTC + 2064 + lane] = sims[lane] * scale;
  } else if (lane < 32) {
    int t2 = lane - 16;
    out[(size_t)bk * OUTC + 2048 + t2] = (src_ids[bk] == t2) ? 0.1f : 0.f;
  }
}

// =======================================================================
extern "C" void kernel_launch(void* const* d_in, const int* in_sizes, int n_in,
                              void* d_out, int out_size, void* d_ws, size_t ws_size,
                              hipStream_t stream) {
  const float* hidden    = (const float*)d_in[0];
  const int*   span_idx  = (const int*)d_in[1];
  const float* span_mask = (const float*)d_in[2];
  const int*   span_start= (const int*)d_in[3];
  const int*   span_end  = (const int*)d_in[4];
  const int*   length    = (const int*)d_in[5];
  const float* slot_emb  = (const float*)d_in[6];
  const float* tgt       = (const float*)d_in[7];
  const int*   src_ids   = (const int*)d_in[8];
  const float* Wih_f = (const float*)d_in[9];
  const float* Whh_f = (const float*)d_in[10];
  const float* bih_f = (const float*)d_in[11];
  const float* bhh_f = (const float*)d_in[12];
  const float* Wih_b = (const float*)d_in[13];
  const float* Whh_b = (const float*)d_in[14];
  const float* bih_b = (const float*)d_in[15];
  const float* bhh_b = (const float*)d_in[16];
  const float* Wps1 = (const float*)d_in[17];
  const float* bps1 = (const float*)d_in[18];
  const float* Wps2 = (const float*)d_in[19];
  const float* bps2 = (const float*)d_in[20];
  const float* Wpc1 = (const float*)d_in[21];
  const float* bpc1 = (const float*)d_in[22];
  const float* Wpc2 = (const float*)d_in[23];
  const float* bpc2 = (const float*)d_in[24];
  float* out = (float*)d_out;

  char* p = (char*)d_ws;
  auto alloc = [&](size_t bytes) -> void* {
    void* r = (void*)p;
    p += (bytes + 255) & ~(size_t)255;
    return r;
  };
  // BIG1: G2 bf16 [L][NSEQ][4096] (64 MB), dead after recurrence -> P partials
  char*  BIG1  = (char*)alloc((size_t)XROWS * 4096 * 2);
  // BIG2: Hh/Hl bf16 splits of hidden (67.1 MB)
  char*  BIG2  = (char*)alloc((size_t)2 * B_ * S_ * D_ * 2);
  float* hst   = (float*)alloc((size_t)2 * NSEQ * H_ * 4);
  float* cst   = (float*)alloc((size_t)2 * NSEQ * H_ * 4);
  u16*   hbfA  = (u16*)alloc((size_t)2 * NSEQ * H_ * 2);
  u16*   hbfB  = (u16*)alloc((size_t)2 * NSEQ * H_ * 2);
  float* sf    = (float*)alloc((size_t)NSEQ * 1024 * 4);
  u16*   sfh   = (u16*)alloc((size_t)NSEQ * 1024 * 2);
  u16*   sfl   = (u16*)alloc((size_t)NSEQ * 1024 * 2);
  float* attn_f= (float*)alloc((size_t)NSEQ * S_ * 4);
  float* CAT   = (float*)alloc((size_t)MROWS * 2048 * 4);
  u16* Wih2_i = (u16*)alloc((size_t)2 * G4H * D_ * 2);
  u16* Whhf_i = (u16*)alloc((size_t)G4H * H_ * 2);
  u16* Whhb_i = (u16*)alloc((size_t)G4H * H_ * 2);
  float* bsumf = (float*)alloc(G4H * 4);
  float* bsumb = (float*)alloc(G4H * 4);
  u16* W1sh = (u16*)alloc((size_t)D_ * D_ * 2); u16* W1sl = (u16*)alloc((size_t)D_ * D_ * 2);
  u16* W2sh = (u16*)alloc((size_t)D_ * D_ * 2); u16* W2sl = (u16*)alloc((size_t)D_ * D_ * 2);
  u16* W1ch = (u16*)alloc((size_t)D_ * D_ * 2); u16* W1cl = (u16*)alloc((size_t)D_ * D_ * 2);
  u16* W2ch = (u16*)alloc((size_t)D_ * D_ * 2); u16* W2cl = (u16*)alloc((size_t)D_ * D_ * 2);
  u16* SEh = (u16*)alloc((size_t)MROWS * D_ * 2); u16* SEl = (u16*)alloc((size_t)MROWS * D_ * 2);
  u16* T1h = (u16*)alloc((size_t)2 * MROWS * D_ * 2);
  u16* T1l = (u16*)alloc((size_t)2 * MROWS * D_ * 2);

  // aliases
  u16*   G2 = (u16*)BIG1;
  float* P  = (float*)BIG1;             // after recurrence
  u16*   Hh = (u16*)BIG2;
  u16*   Hl = Hh + (size_t)B_ * S_ * D_;

  size_t need = (size_t)(p - (char*)d_ws);
  if (need > ws_size) {
    fprintf(stderr, "kernel_launch: ws too small, need %zu have %zu\n", need, ws_size);
    return;
  }

  // ---- weight prep (fused launches) ----
  {
    dim3 g(G4H, 4);
    wprep_kernel<<<g, 256, 0, stream>>>(Wih_f, Wih_b, Whh_f, Whh_b,
                                        Wih2_i, Whhf_i, Whhb_i);
  }
  bsum2_kernel<<<(2 * G4H) / 256, 256, 0, stream>>>(bih_f, bhh_f, bih_b, bhh_b,
                                                    bsumf, bsumb);
  {
    dim3 g((D_ * D_) / 256, 4);
    split4_kernel<<<g, 256, 0, stream>>>(Wps1, Wps2, Wpc1, Wpc2,
                                         W1sh, W1sl, W2sh, W2sl,
                                         W1ch, W1cl, W2ch, W2cl);
  }
  sesplit_kernel<<<(MROWS * D_) / 256, 256, 0, stream>>>(slot_emb, tgt, SEh, SEl);

  // hidden hi/lo split (Hh feeds gathered big GEMM + attn)
  hsplit_kernel<<<(B_ * S_ * D_) / (4 * 256), 256, 0, stream>>>(hidden, Hh, Hl);

  // ---- big input GEMM (gather fused, t-major M, proven structure) ----
  {
    dim3 g(4096 / 128, XROWS / 128);
    big_gemm_kernel<<<g, 256, 0, stream>>>(Hh, span_idx, Wih2_i, G2);
  }

  // ---- bi-LSTM recurrence (last step fuses slot_feats output + split) ----
  for (int t = 0; t < L_; ++t) {
    const u16* hin = (t & 1) ? hbfA : hbfB;
    u16* hout = (t & 1) ? hbfB : hbfA;
    dim3 g(G4H / 64, NSEQ / 64, 2);
    lstm_step_kernel<<<g, 256, 0, stream>>>(hin, Whhf_i, Whhb_i, G2, bsumf, bsumb,
                                            span_mask, hst, cst, hout, sf,
                                            out, sfh, sfl,
                                            t, t == 0 ? 1 : 0, t == L_ - 1 ? 1 : 0);
  }

  // ---- attention (3-term MFMA, f32 scores) + context (exact f32) ----
  {
    dim3 g(B_, S_ / 128);
    attn_mfma_kernel<<<g, 256, 0, stream>>>(sfh, sfl, Hh, Hl,
                                            span_start, span_end, length, attn_f);
  }
  {
    dim3 g(B_, D_ / 128);
    ctx_f32_kernel<<<g, 256, 0, stream>>>(attn_f, hidden, out);
  }

  // ---- MLPs: split-K x 2 branches; G2 dead -> P aliases BIG1 ----
  {
    dim3 g(D_ / 64, (MROWS + 63) / 64, 8);
    dim3 rg((2 * MROWS * D_) / (4 * 256));
    mlp_gemm_kernel<<<g, 256, 0, stream>>>(SEh, SEl, 0, W1sh, W1sl, W1ch, W1cl, P, MROWS);
    mlp_reduce_kernel<<<rg, 256, 0, stream>>>(P, bps1, bpc1, T1h, T1l, nullptr, 0);
    mlp_gemm_kernel<<<g, 256, 0, stream>>>(T1h, T1l, MROWS * D_, W2sh, W2sl, W2ch, W2cl, P, MROWS);
    mlp_reduce_kernel<<<rg, 256, 0, stream>>>(P, bps2, bpc2, nullptr, nullptr, CAT, 1);
  }

  // ---- labels ----
  const float* t_cat = CAT + (size_t)NSEQ * 2048;
  labels_kernel<<<NSEQ, 64, 0, stream>>>(CAT, t_cat, src_ids, out);
}

// Round 9
// 637.351 us; speedup vs baseline: 1.0398x; 1.0040x over previous
//
#include <hip/hip_runtime.h>
#include <cstdio>

#define B_ 32
#define S_ 512
#define D_ 1024
#define H_ 512
#define K_ 16
#define L_ 16
#define NT_ 16
#define NSEQ 512      // B*K
#define XROWS 8192    // NSEQ*L
#define G4H 2048      // 4*H
#define OUTC 2080
#define MROWS 528     // NSEQ + NT

typedef unsigned short u16;
typedef __bf16 bf16x8 __attribute__((ext_vector_type(8)));
typedef float f32x4 __attribute__((ext_vector_type(4)));

__device__ inline u16 f2b(float f) {
  union { float f; unsigned u; } x; x.f = f;
  unsigned r = x.u + 0x7FFFu + ((x.u >> 16) & 1u);
  return (u16)(r >> 16);
}
__device__ inline float b2f(u16 h) {
  union { unsigned u; float f; } c; c.u = ((unsigned)h) << 16;
  return c.f;
}
__device__ inline float sigf(float x) { return 1.0f / (1.0f + expf(-x)); }
__device__ inline float wredsum(float v) {
#pragma unroll
  for (int off = 32; off > 0; off >>= 1) v += __shfl_xor(v, off);
  return v;
}
// async global->LDS, 16B/lane; dest = wave-uniform base + lane*16 (linear)
__device__ inline void gl16(const u16* g, u16* l) {
  __builtin_amdgcn_global_load_lds(
      (const __attribute__((address_space(1))) unsigned int*)g,
      (__attribute__((address_space(3))) unsigned int*)l, 16, 0, 0);
}
#define VMCNT(N) asm volatile("s_waitcnt vmcnt(" #N ")" ::: "memory")

// ---------------- split f32 -> hi+lo bf16 ----------------
__global__ __launch_bounds__(256) void split_kernel(const float* __restrict__ in,
                                                    u16* __restrict__ hi,
                                                    u16* __restrict__ lo, int n) {
  int i = blockIdx.x * 256 + threadIdx.x;
  if (i >= n) return;
  float x = in[i];
  u16 h = f2b(x);
  hi[i] = h;
  lo[i] = f2b(x - b2f(h));
}

// slot_emb + tgt -> SEh/SEl in one launch (contiguous dest)
__global__ __launch_bounds__(256) void sesplit_kernel(const float* __restrict__ se,
                                                      const float* __restrict__ tg,
                                                      u16* __restrict__ hi,
                                                      u16* __restrict__ lo) {
  int i = blockIdx.x * 256 + threadIdx.x;    // < MROWS*D
  float x = (i < NSEQ * D_) ? se[i] : tg[i - NSEQ * D_];
  u16 h = f2b(x);
  hi[i] = h;
  lo[i] = f2b(x - b2f(h));
}

// 4 MLP weights in one launch: blockIdx.y selects
__global__ __launch_bounds__(256) void split4_kernel(
    const float* __restrict__ s0, const float* __restrict__ s1,
    const float* __restrict__ s2, const float* __restrict__ s3,
    u16* __restrict__ h0, u16* __restrict__ l0,
    u16* __restrict__ h1, u16* __restrict__ l1,
    u16* __restrict__ h2, u16* __restrict__ l2,
    u16* __restrict__ h3, u16* __restrict__ l3) {
  const float* src = blockIdx.y == 0 ? s0 : blockIdx.y == 1 ? s1 : blockIdx.y == 2 ? s2 : s3;
  u16* hi = blockIdx.y == 0 ? h0 : blockIdx.y == 1 ? h1 : blockIdx.y == 2 ? h2 : h3;
  u16* lo = blockIdx.y == 0 ? l0 : blockIdx.y == 1 ? l1 : blockIdx.y == 2 ? l2 : l3;
  int i = blockIdx.x * 256 + threadIdx.x;
  float x = src[i];
  u16 h = f2b(x);
  hi[i] = h;
  lo[i] = f2b(x - b2f(h));
}

__global__ __launch_bounds__(256) void hsplit_kernel(const float* __restrict__ in,
                                                     u16* __restrict__ hi,
                                                     u16* __restrict__ lo) {
  size_t i = ((size_t)blockIdx.x * 256 + threadIdx.x) * 4;
  float4 v = *reinterpret_cast<const float4*>(in + i);
  float a[4] = {v.x, v.y, v.z, v.w};
#pragma unroll
  for (int j = 0; j < 4; ++j) {
    u16 h = f2b(a[j]);
    hi[i + j] = h;
    lo[i + j] = f2b(a[j] - b2f(h));
  }
}

// interleave-cast all 4 LSTM weights: y = 0: Wih_f, 1: Wih_b, 2: Whh_f, 3: Whh_b
__global__ __launch_bounds__(256) void wprep_kernel(
    const float* __restrict__ Wihf, const float* __restrict__ Wihb,
    const float* __restrict__ Whhf, const float* __restrict__ Whhb,
    u16* __restrict__ Wih2_i, u16* __restrict__ Whhf_i, u16* __restrict__ Whhb_i) {
  int y = blockIdx.y;
  const float* W = y == 0 ? Wihf : y == 1 ? Wihb : y == 2 ? Whhf : Whhb;
  int Kd = (y < 2) ? D_ : H_;
  u16* dst = y == 0 ? Wih2_i : y == 1 ? (Wih2_i + (size_t)G4H * D_) : y == 2 ? Whhf_i : Whhb_i;
  int rp = blockIdx.x;
  int j = rp >> 2, g = rp & 3;
  const float* src = W + ((size_t)(g * H_ + j)) * Kd;
  u16* d = dst + (size_t)rp * Kd;
  for (int k = threadIdx.x; k < Kd; k += 256) d[k] = f2b(src[k]);
}

// both interleaved biases in one launch
__global__ __launch_bounds__(256) void bsum2_kernel(
    const float* __restrict__ bihf, const float* __restrict__ bhhf,
    const float* __restrict__ bihb, const float* __restrict__ bhhb,
    float* __restrict__ bsumf, float* __restrict__ bsumb) {
  int i = blockIdx.x * 256 + threadIdx.x;    // < 2*G4H
  int dir = i >> 11;
  int rp = i & (G4H - 1);
  int j = rp >> 2, g = rp & 3;
  const float* bi = dir ? bihb : bihf;
  const float* bh = dir ? bhhb : bhhf;
  float v = bi[g * H_ + j] + bh[g * H_ + j];
  (dir ? bsumb : bsumf)[rp] = v;
}

// ---- big input GEMM, gather fused, linear LDS, 2-buf counted-vmcnt pipeline ----
// M-row' = t*NSEQ + seq: contiguous t-major G2 store AND contiguous step reads.
__global__ __launch_bounds__(256) void big_gemm_kernel(
    const u16* __restrict__ Hh, const int* __restrict__ span_idx,
    const u16* __restrict__ Wih2, u16* __restrict__ G2) {
  __shared__ u16 As[2][128 * 32];
  __shared__ u16 Bs[2][128 * 32];
  const int tid = threadIdx.x;
  const int bn = blockIdx.x * 128, bm = blockIdx.y * 128;
  const int wave = tid >> 6, lane = tid & 63;
  const int wm = (wave >> 1) * 64, wn = (wave & 1) * 64;
  const int fr = lane & 15;
  const int kg = (lane >> 4) * 8;

  const u16* asrc[2];
  const u16* bsrc[2];
  int doff[2];
#pragma unroll
  for (int j = 0; j < 2; ++j) {
    int c = tid + 256 * j;
    int gr = bm + (c >> 2);                 // row' = t*NSEQ + seq
    int t = gr >> 9;
    int seq = gr & 511;
    int b = seq >> 4;
    int sidx = span_idx[seq * L_ + t];
    asrc[j] = Hh + ((size_t)(b * S_ + sidx)) * D_ + (c & 3) * 8;
    bsrc[j] = Wih2 + (size_t)(bn + (c >> 2)) * D_ + (c & 3) * 8;
    doff[j] = (j * 256 + wave * 64) * 8;
  }

  f32x4 acc[4][4] = {};
  auto STAGE = [&](int buf, int k0) {
    gl16(asrc[0] + k0, &As[buf][doff[0]]);
    gl16(asrc[1] + k0, &As[buf][doff[1]]);
    gl16(bsrc[0] + k0, &Bs[buf][doff[0]]);
    gl16(bsrc[1] + k0, &Bs[buf][doff[1]]);
  };
  auto COMPUTE = [&](int buf) {
    bf16x8 af[4], bfr[4];
#pragma unroll
    for (int m = 0; m < 4; ++m)
      af[m] = *reinterpret_cast<const bf16x8*>(&As[buf][(wm + m * 16 + fr) * 32 + kg]);
#pragma unroll
    for (int n = 0; n < 4; ++n)
      bfr[n] = *reinterpret_cast<const bf16x8*>(&Bs[buf][(wn + n * 16 + fr) * 32 + kg]);
#pragma unroll
    for (int m = 0; m < 4; ++m)
#pragma unroll
      for (int n = 0; n < 4; ++n)
        acc[m][n] = __builtin_amdgcn_mfma_f32_16x16x32_bf16(af[m], bfr[n], acc[m][n], 0, 0, 0);
  };

  STAGE(0, 0);
  STAGE(1, 32);
  for (int k = 0; k < D_; k += 64) {
    // phase A: tile k in buf0; stage(k) + stage(k+32) outstanding
    VMCNT(4);                           // wait stage(k); stage(k+32) in flight
    __builtin_amdgcn_s_barrier();
    COMPUTE(0);
    __builtin_amdgcn_s_barrier();       // all waves done reading buf0
    if (k + 64 < D_) {
      STAGE(0, k + 64);
      VMCNT(4);                         // wait stage(k+32); stage(k+64) in flight
    } else {
      VMCNT(0);
    }
    __builtin_amdgcn_s_barrier();
    COMPUTE(1);
    __builtin_amdgcn_s_barrier();
    if (k + 96 < D_) STAGE(1, k + 96);
  }

  const int ci = lane & 15;
  const int r0 = (lane >> 4) * 4;
#pragma unroll
  for (int m = 0; m < 4; ++m)
#pragma unroll
    for (int n = 0; n < 4; ++n) {
      int col = bn + wn + n * 16 + ci;
#pragma unroll
      for (int r = 0; r < 4; ++r) {
        int row = bm + wm + m * 16 + r0 + r;    // t-major row', contiguous
        G2[(size_t)row * 4096 + col] = f2b(acc[m][n][r]);
      }
    }
}

// ---------------- fused recurrent GEMM + LSTM gate step (both dirs via z) ------
// last==1: also write slot_feats to out + sfh/sfl splits.
__global__ __launch_bounds__(256) void lstm_step_kernel(
    const u16* __restrict__ hbf_in,
    const u16* __restrict__ Whhf, const u16* __restrict__ Whhb,
    const u16* __restrict__ G2,
    const float* __restrict__ bsumf, const float* __restrict__ bsumb,
    const float* __restrict__ mask,
    float* __restrict__ hst, float* __restrict__ cst,
    u16* __restrict__ hbf_out,
    float* __restrict__ sf,
    float* __restrict__ out, u16* __restrict__ sfh, u16* __restrict__ sfl,
    int t, int first, int last) {
  __shared__ u16 As[2][64 * 32];
  __shared__ u16 Bs[2][64 * 32];
  const int tid = threadIdx.x;
  const int bz = blockIdx.z;
  const int treal = bz ? (L_ - 1 - t) : t;
  const u16* Whh = bz ? Whhb : Whhf;
  const float* bsum = bz ? bsumb : bsumf;
  const size_t sofs = (size_t)bz * NSEQ * H_;
  const int bm = blockIdx.y * 64, bn = blockIdx.x * 64;
  const int wave = tid >> 6, lane = tid & 63;
  const int wm = (wave >> 1) * 32, wn = (wave & 1) * 32;
  f32x4 acc[2][2] = {};
  const int fr = lane & 15;
  const int kg = (lane >> 4) * 8;

  if (!first) {
    const int c = tid;
    const u16* asrc = hbf_in + sofs + (size_t)(bm + (c >> 2)) * H_ + (c & 3) * 8;
    const u16* bsrc = Whh + (size_t)(bn + (c >> 2)) * H_ + (c & 3) * 8;
    const int doff = wave * 512;
    auto STAGE = [&](int buf, int k0) {
      gl16(asrc + k0, &As[buf][doff]);
      gl16(bsrc + k0, &Bs[buf][doff]);
    };
    auto COMPUTE = [&](int buf) {
      bf16x8 af[2], bfr[2];
#pragma unroll
      for (int m = 0; m < 2; ++m)
        af[m] = *reinterpret_cast<const bf16x8*>(&As[buf][(wm + m * 16 + fr) * 32 + kg]);
#pragma unroll
      for (int n = 0; n < 2; ++n)
        bfr[n] = *reinterpret_cast<const bf16x8*>(&Bs[buf][(wn + n * 16 + fr) * 32 + kg]);
#pragma unroll
      for (int m = 0; m < 2; ++m)
#pragma unroll
        for (int n = 0; n < 2; ++n)
          acc[m][n] = __builtin_amdgcn_mfma_f32_16x16x32_bf16(af[m], bfr[n], acc[m][n], 0, 0, 0);
    };
    STAGE(0, 0);
    STAGE(1, 32);
    for (int k = 0; k < H_; k += 64) {
      VMCNT(2);
      __builtin_amdgcn_s_barrier();
      COMPUTE(0);
      __builtin_amdgcn_s_barrier();
      if (k + 64 < H_) {
        STAGE(0, k + 64);
        VMCNT(2);
      } else {
        VMCNT(0);
      }
      __builtin_amdgcn_s_barrier();
      COMPUTE(1);
      __builtin_amdgcn_s_barrier();
      if (k + 96 < H_) STAGE(1, k + 96);
    }
  }

  const int ci = lane & 15;
  const int r0 = (lane >> 4) * 4;
  const int q = lane & 3;
#pragma unroll
  for (int m = 0; m < 2; ++m)
#pragma unroll
    for (int n = 0; n < 2; ++n) {
      int c = bn + wn + n * 16 + ci;
      int rowbase = bm + wm + m * 16 + r0;
      float val[4];
#pragma unroll
      for (int r = 0; r < 4; ++r) {
        int nrow = rowbase + r;
        float g2 = b2f(G2[((size_t)treal * NSEQ + nrow) * 4096 + (size_t)bz * 2048 + c]);
        val[r] = acc[m][n][r] + g2 + bsum[c];
      }
      float x1[4], x2[4], x3[4];
#pragma unroll
      for (int r = 0; r < 4; ++r) {
        x1[r] = __shfl_xor(val[r], 1);
        x2[r] = __shfl_xor(val[r], 2);
        x3[r] = __shfl_xor(x1[r], 2);
      }
      if (q == 0) {
        int j = c >> 2;
#pragma unroll
        for (int r = 0; r < 4; ++r) {
          int nrow = rowbase + r;
          float gi = val[r], gf = x1[r], gg = x2[r], go = x3[r];
          float mv = mask[nrow * L_ + treal];
          size_t sidx = sofs + (size_t)nrow * H_ + j;
          float co = first ? 0.f : cst[sidx];
          float ho = first ? 0.f : hst[sidx];
          float cn = sigf(gf) * co + sigf(gi) * tanhf(gg);
          float hn = sigf(go) * tanhf(cn);
          float hnew = mv * hn + (1.f - mv) * ho;
          float cnew = mv * cn + (1.f - mv) * co;
          hst[sidx] = hnew;
          cst[sidx] = cnew;
          hbf_out[sidx] = f2b(hnew);
          size_t fidx = (size_t)nrow * 1024 + bz * 512 + j;
          float contrib = hnew * mv;
          float snew = first ? contrib : sf[fidx] + contrib;
          sf[fidx] = snew;
          if (last) {
            out[(size_t)nrow * OUTC + bz * 512 + j] = snew;
            u16 hh = f2b(snew);
            sfh[fidx] = hh;
            sfl[fidx] = f2b(snew - b2f(hh));
          }
        }
      }
    }
}

// ---------------- attn = sf . hidden^T (3-term), masked, f32 out ----------------
__global__ __launch_bounds__(256) void attn_mfma_kernel(
    const u16* __restrict__ sfh, const u16* __restrict__ sfl,
    const u16* __restrict__ Hh, const u16* __restrict__ Hl,
    const int* __restrict__ sstart, const int* __restrict__ send,
    const int* __restrict__ len,
    float* __restrict__ attn_f) {
  __shared__ u16 Bh[128 * 32];
  __shared__ u16 Bl[128 * 32];
  const int b = blockIdx.x;
  const int s0 = blockIdx.y * 128;
  const int tid = threadIdx.x;
  const int wave = tid >> 6, lane = tid & 63;
  const int fr = lane & 15;
  const int kg = (lane >> 4) * 8;
  f32x4 acc[2] = {};

  const u16* hsrc[2];
  const u16* lsrc[2];
  u16* hdst[2];
  u16* ldst[2];
#pragma unroll
  for (int j = 0; j < 2; ++j) {
    int c = tid + 256 * j;
    size_t goff = ((size_t)b * S_ + s0 + (c >> 2)) * D_ + (c & 3) * 8;
    hsrc[j] = Hh + goff;
    lsrc[j] = Hl + goff;
    int ub = (wave * 64 + 256 * j) * 8;
    hdst[j] = Bh + ub;
    ldst[j] = Bl + ub;
  }

  for (int k0 = 0; k0 < D_; k0 += 32) {
    gl16(hsrc[0] + k0, hdst[0]);
    gl16(hsrc[1] + k0, hdst[1]);
    gl16(lsrc[0] + k0, ldst[0]);
    gl16(lsrc[1] + k0, ldst[1]);
    __syncthreads();
    size_t aoff = ((size_t)b * 16 + fr) * D_ + k0 + kg;
    bf16x8 ah = *reinterpret_cast<const bf16x8*>(sfh + aoff);
    bf16x8 al = *reinterpret_cast<const bf16x8*>(sfl + aoff);
#pragma unroll
    for (int nt = 0; nt < 2; ++nt) {
      bf16x8 bh = *reinterpret_cast<const bf16x8*>(&Bh[(wave * 32 + nt * 16 + fr) * 32 + kg]);
      bf16x8 bl = *reinterpret_cast<const bf16x8*>(&Bl[(wave * 32 + nt * 16 + fr) * 32 + kg]);
      acc[nt] = __builtin_amdgcn_mfma_f32_16x16x32_bf16(ah, bh, acc[nt], 0, 0, 0);
      acc[nt] = __builtin_amdgcn_mfma_f32_16x16x32_bf16(ah, bl, acc[nt], 0, 0, 0);
      acc[nt] = __builtin_amdgcn_mfma_f32_16x16x32_bf16(al, bh, acc[nt], 0, 0, 0);
    }
    __syncthreads();
  }
  const int ln = len[b];
#pragma unroll
  for (int nt = 0; nt < 2; ++nt) {
    int s = s0 + wave * 32 + nt * 16 + (lane & 15);
#pragma unroll
    for (int r = 0; r < 4; ++r) {
      int krow = (lane >> 4) * 4 + r;
      int bk = b * 16 + krow;
      int st = sstart[bk], en = send[bk];
      bool cm = (s < st) || ((s > en) && (s < ln));
      attn_f[(size_t)bk * S_ + s] = cm ? acc[nt][r] : 0.f;
    }
  }
}

// ---------------- context (exact f32): out[.,1024+d] = sum_s attn*hidden ----
__global__ __launch_bounds__(256) void ctx_f32_kernel(
    const float* __restrict__ attn_f, const float* __restrict__ hidden,
    float* __restrict__ out) {
  __shared__ float att[16 * 512];   // 32 KB, rows 16B-aligned
  const int b = blockIdx.x;
  const int d0 = blockIdx.y * 128;
  const int tid = threadIdx.x;
  for (int i = tid; i < 16 * 512; i += 256)
    att[i] = attn_f[((size_t)b * 16 + (i >> 9)) * S_ + (i & 511)];
  __syncthreads();
  const int d = d0 + (tid & 127);
  const int sh = tid >> 7;
  float acc[16] = {};
  const float* hp = hidden + ((size_t)b * S_ + sh * 256) * D_ + d;
  for (int s4 = 0; s4 < 64; ++s4) {
    float h0 = hp[(size_t)(s4 * 4 + 0) * D_];
    float h1 = hp[(size_t)(s4 * 4 + 1) * D_];
    float h2 = hp[(size_t)(s4 * 4 + 2) * D_];
    float h3 = hp[(size_t)(s4 * 4 + 3) * D_];
    int si = sh * 256 + s4 * 4;
#pragma unroll
    for (int kr = 0; kr < 16; ++kr) {
      float4 a4 = *reinterpret_cast<const float4*>(&att[kr * 512 + si]);
      acc[kr] += a4.x * h0 + a4.y * h1 + a4.z * h2 + a4.w * h3;
    }
  }
  __syncthreads();
  float* red = att;                 // reuse: [2][16][128]
#pragma unroll
  for (int kr = 0; kr < 16; ++kr) red[(sh * 16 + kr) * 128 + (tid & 127)] = acc[kr];
  __syncthreads();
  if (sh == 0) {
#pragma unroll
    for (int kr = 0; kr < 16; ++kr)
      out[((size_t)b * 16 + kr) * OUTC + 1024 + d] =
          red[kr * 128 + (tid & 127)] + red[(16 + kr) * 128 + (tid & 127)];
  }
}

// ---------------- MLP split-K GEMM (3-term partials), 2-buf pipeline ---------
__global__ __launch_bounds__(256) void mlp_gemm_kernel(
    const u16* __restrict__ Ah, const u16* __restrict__ Al, int a_br_stride,
    const u16* __restrict__ B0h, const u16* __restrict__ B0l,
    const u16* __restrict__ B1h, const u16* __restrict__ B1l,
    float* __restrict__ P, int M) {
  __shared__ u16 Ash[2][64 * 32];
  __shared__ u16 Asl[2][64 * 32];
  __shared__ u16 Bsh[2][64 * 32];
  __shared__ u16 Bsl[2][64 * 32];
  const int tid = threadIdx.x;
  const int zz = blockIdx.z;
  const int br = zz >> 2, ks = zz & 3;
  const u16* Ah_ = Ah + (size_t)br * a_br_stride;
  const u16* Al_ = Al + (size_t)br * a_br_stride;
  const u16* Bh = br ? B1h : B0h;
  const u16* Bl = br ? B1l : B0l;
  const int bm = blockIdx.y * 64, bn = blockIdx.x * 64;
  const int wave = tid >> 6, lane = tid & 63;
  const int wm = (wave >> 1) * 32, wn = (wave & 1) * 32;
  f32x4 acc[2][2] = {};
  const int fr = lane & 15;
  const int kg = (lane >> 4) * 8;

  const int c = tid;
  int ga = bm + (c >> 2);
  if (ga >= M) ga = M - 1;                  // clamp; OOB rows unused in epilogue
  const u16* ahsrc = Ah_ + (size_t)ga * D_ + (c & 3) * 8;
  const u16* alsrc = Al_ + (size_t)ga * D_ + (c & 3) * 8;
  const u16* bhsrc = Bh + (size_t)(bn + (c >> 2)) * D_ + (c & 3) * 8;
  const u16* blsrc = Bl + (size_t)(bn + (c >> 2)) * D_ + (c & 3) * 8;
  const int doff = wave * 512;

  auto STAGE = [&](int buf, int k0) {
    gl16(ahsrc + k0, &Ash[buf][doff]);
    gl16(alsrc + k0, &Asl[buf][doff]);
    gl16(bhsrc + k0, &Bsh[buf][doff]);
    gl16(blsrc + k0, &Bsl[buf][doff]);
  };
  auto COMPUTE = [&](int buf) {
    bf16x8 afh[2], afl[2], bfh[2], bfl[2];
#pragma unroll
    for (int m = 0; m < 2; ++m) {
      afh[m] = *reinterpret_cast<const bf16x8*>(&Ash[buf][(wm + m * 16 + fr) * 32 + kg]);
      afl[m] = *reinterpret_cast<const bf16x8*>(&Asl[buf][(wm + m * 16 + fr) * 32 + kg]);
    }
#pragma unroll
    for (int n = 0; n < 2; ++n) {
      bfh[n] = *reinterpret_cast<const bf16x8*>(&Bsh[buf][(wn + n * 16 + fr) * 32 + kg]);
      bfl[n] = *reinterpret_cast<const bf16x8*>(&Bsl[buf][(wn + n * 16 + fr) * 32 + kg]);
    }
#pragma unroll
    for (int m = 0; m < 2; ++m)
#pragma unroll
      for (int n = 0; n < 2; ++n) {
        acc[m][n] = __builtin_amdgcn_mfma_f32_16x16x32_bf16(afh[m], bfh[n], acc[m][n], 0, 0, 0);
        acc[m][n] = __builtin_amdgcn_mfma_f32_16x16x32_bf16(afh[m], bfl[n], acc[m][n], 0, 0, 0);
        acc[m][n] = __builtin_amdgcn_mfma_f32_16x16x32_bf16(afl[m], bfh[n], acc[m][n], 0, 0, 0);
      }
  };

  const int kbeg = ks * 256;
  const int kend = kbeg + 256;
  STAGE(0, kbeg);
  STAGE(1, kbeg + 32);
  for (int k = kbeg; k < kend; k += 64) {
    VMCNT(4);
    __builtin_amdgcn_s_barrier();
    COMPUTE(0);
    __builtin_amdgcn_s_barrier();
    if (k + 64 < kend) {
      STAGE(0, k + 64);
      VMCNT(4);
    } else {
      VMCNT(0);
    }
    __builtin_amdgcn_s_barrier();
    COMPUTE(1);
    __builtin_amdgcn_s_barrier();
    if (k + 96 < kend) STAGE(1, k + 96);
  }
  const int ci = lane & 15;
  const int r0 = (lane >> 4) * 4;
#pragma unroll
  for (int m = 0; m < 2; ++m)
#pragma unroll
    for (int n = 0; n < 2; ++n) {
      int col = bn + wn + n * 16 + ci;
#pragma unroll
      for (int r = 0; r < 4; ++r) {
        int row = bm + wm + m * 16 + r0 + r;
        if (row < M)
          P[((size_t)zz * MROWS + row) * D_ + col] = acc[m][n][r];
      }
    }
}

// ---------------- MLP reduce ----------------
__global__ __launch_bounds__(256) void mlp_reduce_kernel(
    const float* __restrict__ P,
    const float* __restrict__ bias0, const float* __restrict__ bias1,
    u16* __restrict__ Oh, u16* __restrict__ Ol,
    float* __restrict__ Cf,
    int mode) {
  int i = blockIdx.x * 256 + threadIdx.x;
  int e = i * 4;
  const int per_br = MROWS * D_;
  int br = e / per_br;
  int rem = e - br * per_br;
  int row = rem >> 10;
  int col = rem & 1023;
  float4 s = {0.f, 0.f, 0.f, 0.f};
#pragma unroll
  for (int ks = 0; ks < 4; ++ks) {
    float4 v = *reinterpret_cast<const float4*>(
        P + ((size_t)(br * 4 + ks) * MROWS + row) * D_ + col);
    s.x += v.x; s.y += v.y; s.z += v.z; s.w += v.w;
  }
  const float* bias = br ? bias1 : bias0;
  s.x += bias[col]; s.y += bias[col + 1]; s.z += bias[col + 2]; s.w += bias[col + 3];
  if (mode == 0) {
    float a[4] = {tanhf(s.x), tanhf(s.y), tanhf(s.z), tanhf(s.w)};
    size_t o = (size_t)br * per_br + (size_t)row * D_ + col;
#pragma unroll
    for (int j = 0; j < 4; ++j) {
      u16 h = f2b(a[j]);
      Oh[o + j] = h;
      Ol[o + j] = f2b(a[j] - b2f(h));
    }
  } else {
    *reinterpret_cast<float4*>(Cf + (size_t)row * 2048 + br * 1024 + col) = s;
  }
}

// ---------------- labels ----------------
__global__ __launch_bounds__(64) void labels_kernel(
    const float* __restrict__ s_cat, const float* __restrict__ t_cat,
    const int* __restrict__ src_ids, float* __restrict__ out) {
  int bk = blockIdx.x, lane = threadIdx.x;
  const float* srow = s_cat + (size_t)bk * 2048;
  float np = 0.f;
  float dots[16], tsq[16];
#pragma unroll
  for (int t = 0; t < 16; ++t) { dots[t] = 0.f; tsq[t] = 0.f; }
  for (int j = lane; j < 2048; j += 64) {
    float sv = srow[j];
    np += sv * sv;
#pragma unroll
    for (int t = 0; t < 16; ++t) {
      float tv = t_cat[t * 2048 + j];
      dots[t] += sv * tv;
      tsq[t] += tv * tv;
    }
  }
  np = wredsum(np);
#pragma unroll
  for (int t = 0; t < 16; ++t) { dots[t] = wredsum(dots[t]); tsq[t] = wredsum(tsq[t]); }
  float sn = fmaxf(sqrtf(np), 1e-8f);
  float ssum = 0.f;
  float sims[16];
#pragma unroll
  for (int t = 0; t < 16; ++t) {
    float tn = fmaxf(sqrtf(tsq[t]), 1e-8f);
    sims[t] = dots[t] / (sn * tn);
    ssum += sims[t];
  }
  float scale = 0.9f / ssum;
  if (lane < 16) {
    out[(size_t)bk * OUTC + 2064 + lane] = sims[lane] * scale;
  } else if (lane < 32) {
    int t2 = lane - 16;
    out[(size_t)bk * OUTC + 2048 + t2] = (src_ids[bk] == t2) ? 0.1f : 0.f;
  }
}

// =======================================================================
extern "C" void kernel_launch(void* const* d_in, const int* in_sizes, int n_in,
                              void* d_out, int out_size, void* d_ws, size_t ws_size,
                              hipStream_t stream) {
  const float* hidden    = (const float*)d_in[0];
  const int*   span_idx  = (const int*)d_in[1];
  const float* span_mask = (const float*)d_in[2];
  const int*   span_start= (const int*)d_in[3];
  const int*   span_end  = (const int*)d_in[4];
  const int*   length    = (const int*)d_in[5];
  const float* slot_emb  = (const float*)d_in[6];
  const float* tgt       = (const float*)d_in[7];
  const int*   src_ids   = (const int*)d_in[8];
  const float* Wih_f = (const float*)d_in[9];
  const float* Whh_f = (const float*)d_in[10];
  const float* bih_f = (const float*)d_in[11];
  const float* bhh_f = (const float*)d_in[12];
  const float* Wih_b = (const float*)d_in[13];
  const float* Whh_b = (const float*)d_in[14];
  const float* bih_b = (const float*)d_in[15];
  const float* bhh_b = (const float*)d_in[16];
  const float* Wps1 = (const float*)d_in[17];
  const float* bps1 = (const float*)d_in[18];
  const float* Wps2 = (const float*)d_in[19];
  const float* bps2 = (const float*)d_in[20];
  const float* Wpc1 = (const float*)d_in[21];
  const float* bpc1 = (const float*)d_in[22];
  const float* Wpc2 = (const float*)d_in[23];
  const float* bpc2 = (const float*)d_in[24];
  float* out = (float*)d_out;

  char* p = (char*)d_ws;
  auto alloc = [&](size_t bytes) -> void* {
    void* r = (void*)p;
    p += (bytes + 255) & ~(size_t)255;
    return r;
  };
  // BIG1: G2 bf16 [L][NSEQ][4096] (64 MB), dead after recurrence -> P partials
  char*  BIG1  = (char*)alloc((size_t)XROWS * 4096 * 2);
  // BIG2: Hh/Hl bf16 splits of hidden (67.1 MB)
  char*  BIG2  = (char*)alloc((size_t)2 * B_ * S_ * D_ * 2);
  float* hst   = (float*)alloc((size_t)2 * NSEQ * H_ * 4);
  float* cst   = (float*)alloc((size_t)2 * NSEQ * H_ * 4);
  u16*   hbfA  = (u16*)alloc((size_t)2 * NSEQ * H_ * 2);
  u16*   hbfB  = (u16*)alloc((size_t)2 * NSEQ * H_ * 2);
  float* sf    = (float*)alloc((size_t)NSEQ * 1024 * 4);
  u16*   sfh   = (u16*)alloc((size_t)NSEQ * 1024 * 2);
  u16*   sfl   = (u16*)alloc((size_t)NSEQ * 1024 * 2);
  float* attn_f= (float*)alloc((size_t)NSEQ * S_ * 4);
  float* CAT   = (float*)alloc((size_t)MROWS * 2048 * 4);
  u16* Wih2_i = (u16*)alloc((size_t)2 * G4H * D_ * 2);
  u16* Whhf_i = (u16*)alloc((size_t)G4H * H_ * 2);
  u16* Whhb_i = (u16*)alloc((size_t)G4H * H_ * 2);
  float* bsumf = (float*)alloc(G4H * 4);
  float* bsumb = (float*)alloc(G4H * 4);
  u16* W1sh = (u16*)alloc((size_t)D_ * D_ * 2); u16* W1sl = (u16*)alloc((size_t)D_ * D_ * 2);
  u16* W2sh = (u16*)alloc((size_t)D_ * D_ * 2); u16* W2sl = (u16*)alloc((size_t)D_ * D_ * 2);
  u16* W1ch = (u16*)alloc((size_t)D_ * D_ * 2); u16* W1cl = (u16*)alloc((size_t)D_ * D_ * 2);
  u16* W2ch = (u16*)alloc((size_t)D_ * D_ * 2); u16* W2cl = (u16*)alloc((size_t)D_ * D_ * 2);
  u16* SEh = (u16*)alloc((size_t)MROWS * D_ * 2); u16* SEl = (u16*)alloc((size_t)MROWS * D_ * 2);
  u16* T1h = (u16*)alloc((size_t)2 * MROWS * D_ * 2);
  u16* T1l = (u16*)alloc((size_t)2 * MROWS * D_ * 2);

  // aliases
  u16*   G2 = (u16*)BIG1;
  float* P  = (float*)BIG1;             // after recurrence
  u16*   Hh = (u16*)BIG2;
  u16*   Hl = Hh + (size_t)B_ * S_ * D_;

  size_t need = (size_t)(p - (char*)d_ws);
  if (need > ws_size) {
    fprintf(stderr, "kernel_launch: ws too small, need %zu have %zu\n", need, ws_size);
    return;
  }

  // ---- weight prep (fused launches) ----
  {
    dim3 g(G4H, 4);
    wprep_kernel<<<g, 256, 0, stream>>>(Wih_f, Wih_b, Whh_f, Whh_b,
                                        Wih2_i, Whhf_i, Whhb_i);
  }
  bsum2_kernel<<<(2 * G4H) / 256, 256, 0, stream>>>(bih_f, bhh_f, bih_b, bhh_b,
                                                    bsumf, bsumb);
  {
    dim3 g((D_ * D_) / 256, 4);
    split4_kernel<<<g, 256, 0, stream>>>(Wps1, Wps2, Wpc1, Wpc2,
                                         W1sh, W1sl, W2sh, W2sl,
                                         W1ch, W1cl, W2ch, W2cl);
  }
  sesplit_kernel<<<(MROWS * D_) / 256, 256, 0, stream>>>(slot_emb, tgt, SEh, SEl);

  // hidden hi/lo split (Hh feeds gathered big GEMM + attn)
  hsplit_kernel<<<(B_ * S_ * D_) / (4 * 256), 256, 0, stream>>>(hidden, Hh, Hl);

  // ---- big input GEMM (gather fused, t-major M, 2-buf counted-vmcnt) ----
  {
    dim3 g(4096 / 128, XROWS / 128);
    big_gemm_kernel<<<g, 256, 0, stream>>>(Hh, span_idx, Wih2_i, G2);
  }

  // ---- bi-LSTM recurrence (last step fuses slot_feats output + split) ----
  for (int t = 0; t < L_; ++t) {
    const u16* hin = (t & 1) ? hbfA : hbfB;
    u16* hout = (t & 1) ? hbfB : hbfA;
    dim3 g(G4H / 64, NSEQ / 64, 2);
    lstm_step_kernel<<<g, 256, 0, stream>>>(hin, Whhf_i, Whhb_i, G2, bsumf, bsumb,
                                            span_mask, hst, cst, hout, sf,
                                            out, sfh, sfl,
                                            t, t == 0 ? 1 : 0, t == L_ - 1 ? 1 : 0);
  }

  // ---- attention (3-term MFMA, f32 scores) + context (exact f32) ----
  {
    dim3 g(B_, S_ / 128);
    attn_mfma_kernel<<<g, 256, 0, stream>>>(sfh, sfl, Hh, Hl,
                                            span_start, span_end, length, attn_f);
  }
  {
    dim3 g(B_, D_ / 128);
    ctx_f32_kernel<<<g, 256, 0, stream>>>(attn_f, hidden, out);
  }

  // ---- MLPs: split-K x 2 branches; G2 dead -> P aliases BIG1 ----
  {
    dim3 g(D_ / 64, (MROWS + 63) / 64, 8);
    dim3 rg((2 * MROWS * D_) / (4 * 256));
    mlp_gemm_kernel<<<g, 256, 0, stream>>>(SEh, SEl, 0, W1sh, W1sl, W1ch, W1cl, P, MROWS);
    mlp_reduce_kernel<<<rg, 256, 0, stream>>>(P, bps1, bpc1, T1h, T1l, nullptr, 0);
    mlp_gemm_kernel<<<g, 256, 0, stream>>>(T1h, T1l, MROWS * D_, W2sh, W2sl, W2ch, W2cl, P, MROWS);
    mlp_reduce_kernel<<<rg, 256, 0, stream>>>(P, bps2, bpc2, nullptr, nullptr, CAT, 1);
  }

  // ---- labels ----
  const float* t_cat = CAT + (size_t)NSEQ * 2048;
  labels_kernel<<<NSEQ, 64, 0, stream>>>(CAT, t_cat, src_ids, out);
}